// Round 13
// baseline (236.821 us; speedup 1.0000x reference)
//
#include <hip/hip_runtime.h>
#include <cstdint>
#include <cstddef>

typedef unsigned short u16;
typedef __attribute__((ext_vector_type(4))) float f32x4;
typedef __attribute__((ext_vector_type(8))) short bf16x8;

#define SEQT 2048
#define DIMN 2048

__device__ __forceinline__ float bf2f(u16 h){
  union { unsigned int u; float f; } v; v.u = ((unsigned int)h) << 16; return v.f;
}
__device__ __forceinline__ u16 f2bf(float f){
  union { float f; unsigned int u; } v; v.f = f;
  unsigned int r = v.u + 0x7fffu + ((v.u >> 16) & 1u);
  return (u16)(r >> 16);
}
__device__ __forceinline__ float fexp2(float x){
  float r;
  asm("v_exp_f32 %0, %1" : "=v"(r) : "v"(x));
  return r;
}
__device__ __forceinline__ unsigned int cvtpk(float lo, float hi){
  unsigned int r;
  asm("v_cvt_pk_bf16_f32 %0, %1, %2" : "=v"(r) : "v"(lo), "v"(hi));
  return r;
}

typedef const __attribute__((address_space(1))) unsigned int* gas1_t;
typedef __attribute__((address_space(3))) unsigned int* las3_t;
__device__ __forceinline__ void gload_lds16(const void* g, void* l){
  __builtin_amdgcn_global_load_lds((gas1_t)g, (las3_t)l, 16, 0, 0);
}

// ---------------------------------------------------------------------------
// Generic NT GEMM: C[m,n] = sum_k A[m,k]*B[n,k], A:(M,lda) bf16, B:(N,K) bf16.
// BM=128, BN=128; 256 threads = 4 waves 2x2, each 64x64 (4x4 frags).
// EPI: 0 f32 store (+z-offset, split-K), 1 bf16 store, 4 f32 = Xres+SC[col]*acc
// DUAL: adds a K2=32 tail  acc += A2 @ B2^T  (reg-direct, no LDS).
// ---------------------------------------------------------------------------
template<int BK, int EPI, bool DUAL = false>
__global__ __launch_bounds__(256, 2) void gemm_nt(
    const u16* __restrict__ A, const u16* __restrict__ B, void* __restrict__ Cv,
    int M, int N, int K, int lda, const float* __restrict__ Xres,
    const float* __restrict__ SC, const u16* __restrict__ A2,
    const u16* __restrict__ B2)
{
  __shared__ u16 As[128 * BK];
  __shared__ u16 Bs[128 * BK];
  constexpr int ITER = (128 * BK) / 2048;
  constexpr int GM = BK / 8 - 1;
  const int t = threadIdx.x;
  const int w = t >> 6, l = t & 63;
  const int lr = l & 15, lg = l >> 4;
  const int brow = blockIdx.x << 7, bcol = blockIdx.y << 7;
  const int wr = (w >> 1) << 6, wc = (w & 1) << 6;
  const int Kc = K / gridDim.z;
  const int kbeg = blockIdx.z * Kc;
  const int kend = kbeg + Kc;
  f32x4 acc[4][4] = {};
  for (int k0 = kbeg; k0 < kend; k0 += BK) {
    __syncthreads();
#pragma unroll
    for (int i = 0; i < ITER; ++i) {
      int eo = i * 2048 + t * 8;
      int row = eo / BK;
      int cg = (eo & (BK - 1)) >> 3;
      int scol = ((cg ^ row) & GM) << 3;       // pre-swizzled global source
      gload_lds16(A + (size_t)(brow + row) * lda + k0 + scol, &As[eo]);
      gload_lds16(B + (size_t)(bcol + row) * K + k0 + scol, &Bs[eo]);
    }
    __syncthreads();
#pragma unroll
    for (int ks = 0; ks < BK / 32; ++ks) {
      bf16x8 aF[4], bF[4];
#pragma unroll
      for (int m = 0; m < 4; ++m) {
        int row = wr + m * 16 + lr;
        int kg = ks * 4 + lg;
        aF[m] = *(const bf16x8*)&As[row * BK + (((kg ^ row) & GM) << 3)];
      }
#pragma unroll
      for (int n = 0; n < 4; ++n) {
        int row = wc + n * 16 + lr;
        int kg = ks * 4 + lg;
        bF[n] = *(const bf16x8*)&Bs[row * BK + (((kg ^ row) & GM) << 3)];
      }
#pragma unroll
      for (int m = 0; m < 4; ++m)
#pragma unroll
        for (int n = 0; n < 4; ++n)
          acc[m][n] = __builtin_amdgcn_mfma_f32_16x16x32_bf16(aF[m], bF[n], acc[m][n], 0, 0, 0);
    }
  }
  if constexpr (DUAL) {
    bf16x8 aF2[4], bF2[4];
#pragma unroll
    for (int m = 0; m < 4; ++m)
      aF2[m] = *(const bf16x8*)(A2 + (size_t)(brow + wr + m * 16 + lr) * 32 + lg * 8);
#pragma unroll
    for (int n = 0; n < 4; ++n)
      bF2[n] = *(const bf16x8*)(B2 + (size_t)(bcol + wc + n * 16 + lr) * 32 + lg * 8);
#pragma unroll
    for (int m = 0; m < 4; ++m)
#pragma unroll
      for (int n = 0; n < 4; ++n)
        acc[m][n] = __builtin_amdgcn_mfma_f32_16x16x32_bf16(aF2[m], bF2[n], acc[m][n], 0, 0, 0);
  }
  const size_t zoff = (size_t)blockIdx.z * (size_t)M * (size_t)N;
#pragma unroll
  for (int m = 0; m < 4; ++m)
#pragma unroll
    for (int n = 0; n < 4; ++n)
#pragma unroll
      for (int j = 0; j < 4; ++j) {
        int row = brow + wr + m * 16 + lg * 4 + j;
        int col = bcol + wc + n * 16 + lr;
        float v = acc[m][n][j];
        if constexpr (EPI == 0) ((float*)Cv)[zoff + (size_t)row * N + col] = v;
        else if constexpr (EPI == 1) ((u16*)Cv)[(size_t)row * N + col] = f2bf(v);
        else {
          float xo = Xres[(size_t)row * N + col];
          ((float*)Cv)[(size_t)row * N + col] = xo + SC[col] * v;
        }
      }
}

// ---------------------------------------------------------------------------
// hop2k: k16 = rms_HEPS_per_head( rb2[:, :256] @ kuA^T ).  4x1 wave layout:
// each wave owns 32 rows x 128 cols (one kv-head per blockIdx.y) so the
// per-row sum-of-squares is ENTIRELY intra-wave.  [VALIDATED R9]
// ---------------------------------------------------------------------------
__global__ __launch_bounds__(256, 2) void hop2k_k(
    const u16* __restrict__ rb2, const u16* __restrict__ kuA,
    u16* __restrict__ k16)
{
  __shared__ u16 As[128 * 64];
  __shared__ u16 Bs[128 * 64];
  const int t = threadIdx.x, w = t >> 6, l = t & 63;
  const int lr = l & 15, lg = l >> 4;
  const int brow = blockIdx.x << 7;
  const int bcol = blockIdx.y << 7;            // one kv-head per y
  const u16* B = kuA + (size_t)bcol * 256;
  const int wr2 = w << 5;                      // wave: 32 rows x 128 cols
  f32x4 acc[2][8] = {};
  for (int k0 = 0; k0 < 256; k0 += 64) {
    __syncthreads();
#pragma unroll
    for (int i = 0; i < 4; ++i) {
      int eo = i * 2048 + t * 8;
      int row = eo >> 6, cg = (eo >> 3) & 7;
      int scol = ((cg ^ row) & 7) << 3;
      gload_lds16(rb2 + (size_t)(brow + row) * 512 + k0 + scol, &As[eo]);
      gload_lds16(B + (size_t)row * 256 + k0 + scol, &Bs[eo]);
    }
    __syncthreads();
#pragma unroll
    for (int ks = 0; ks < 2; ++ks) {
      bf16x8 aF[2], bF[8];
#pragma unroll
      for (int m = 0; m < 2; ++m) {
        int row = wr2 + m * 16 + lr, kg = ks * 4 + lg;
        aF[m] = *(const bf16x8*)&As[(row << 6) + (((kg ^ row) & 7) << 3)];
      }
#pragma unroll
      for (int n = 0; n < 8; ++n) {
        int row = n * 16 + lr, kg = ks * 4 + lg;
        bF[n] = *(const bf16x8*)&Bs[(row << 6) + (((kg ^ row) & 7) << 3)];
      }
#pragma unroll
      for (int m = 0; m < 2; ++m)
#pragma unroll
        for (int n = 0; n < 8; ++n)
          acc[m][n] = __builtin_amdgcn_mfma_f32_16x16x32_bf16(aF[m], bF[n], acc[m][n], 0, 0, 0);
    }
  }
#pragma unroll
  for (int m = 0; m < 2; ++m)
#pragma unroll
    for (int j = 0; j < 4; ++j) {
      float s = 0.f;
#pragma unroll
      for (int n = 0; n < 8; ++n) { float v = acc[m][n][j]; s += v * v; }
#pragma unroll
      for (int mm = 1; mm < 16; mm <<= 1) s += __shfl_xor(s, mm);
      float rs = rsqrtf(s * (1.0f / 128.0f) + 1.1920929e-07f);
      int row = brow + wr2 + m * 16 + lg * 4 + j;
#pragma unroll
      for (int n = 0; n < 8; ++n)
        k16[(size_t)row * 512 + bcol + n * 16 + lr] = f2bf(acc[m][n][j] * rs);
    }
}

// ---------------------------------------------------------------------------
// hop2q [VALIDATED R12]: q16 = gain*scale*rope( rms_HEPS( rb1[:, :256]
// @ qA^T ) ) per head.  4x1 layout; one head per blockIdx.y.
// ---------------------------------------------------------------------------
__global__ __launch_bounds__(256, 2) void hop2q_k(
    const u16* __restrict__ rb1, const u16* __restrict__ qA,
    u16* __restrict__ q16, const float* __restrict__ gain)
{
  __shared__ u16 As[128 * 64];
  __shared__ u16 Bs[128 * 64];
  const int t = threadIdx.x, w = t >> 6, l = t & 63;
  const int lr = l & 15, lg = l >> 4;
  const int brow = blockIdx.x << 7;
  const int hh = blockIdx.y;                   // head
  const u16* B = qA + ((size_t)hh << 7) * 256;
  const int wr2 = w << 5;
  f32x4 acc[2][8] = {};
  for (int k0 = 0; k0 < 256; k0 += 64) {
    __syncthreads();
#pragma unroll
    for (int i = 0; i < 4; ++i) {
      int eo = i * 2048 + t * 8;
      int row = eo >> 6, cg = (eo >> 3) & 7;
      int scol = ((cg ^ row) & 7) << 3;
      gload_lds16(rb1 + (size_t)(brow + row) * 512 + k0 + scol, &As[eo]);
      gload_lds16(B + (size_t)row * 256 + k0 + scol, &Bs[eo]);
    }
    __syncthreads();
#pragma unroll
    for (int ks = 0; ks < 2; ++ks) {
      bf16x8 aF[2], bF[8];
#pragma unroll
      for (int m = 0; m < 2; ++m) {
        int row = wr2 + m * 16 + lr, kg = ks * 4 + lg;
        aF[m] = *(const bf16x8*)&As[(row << 6) + (((kg ^ row) & 7) << 3)];
      }
#pragma unroll
      for (int n = 0; n < 8; ++n) {
        int row = n * 16 + lr, kg = ks * 4 + lg;
        bF[n] = *(const bf16x8*)&Bs[(row << 6) + (((kg ^ row) & 7) << 3)];
      }
#pragma unroll
      for (int m = 0; m < 2; ++m)
#pragma unroll
        for (int n = 0; n < 8; ++n)
          acc[m][n] = __builtin_amdgcn_mfma_f32_16x16x32_bf16(aF[m], bF[n], acc[m][n], 0, 0, 0);
    }
  }
  const float gm = gain[hh] * 0.08838834764831845f * 1.4426950408889634f; // 1/sqrt(128)*log2e
#pragma unroll
  for (int m = 0; m < 2; ++m)
#pragma unroll
    for (int j = 0; j < 4; ++j) {
      float s = 0.f;
#pragma unroll
      for (int n = 0; n < 8; ++n) { float v = acc[m][n][j]; s += v * v; }
#pragma unroll
      for (int mm = 1; mm < 16; mm <<= 1) s += __shfl_xor(s, mm);
      float rs = rsqrtf(s * (1.0f / 128.0f) + 1.1920929e-07f) * gm;
      int row = brow + wr2 + m * 16 + lg * 4 + j;   // token position
#pragma unroll
      for (int n = 0; n < 2; ++n) {
        float fr = __expf(-(float)(n * 16 + lr) * 0.28782313662425574f); // ln(1e4)/32
        float f = (float)row * fr;
        float c = cosf(f), sn = sinf(f);
        float a1 = acc[m][n][j], a2 = acc[m][n + 2][j];
        acc[m][n][j] = a1 * c + a2 * sn;
        acc[m][n + 2][j] = a2 * c - a1 * sn;
      }
#pragma unroll
      for (int n = 0; n < 8; ++n)
        q16[(size_t)row * 2048 + (hh << 7) + n * 16 + lr] = f2bf(acc[m][n][j] * rs);
    }
}

// ---------------------------------------------------------------------------
// Fused MLP middle: parts[z] = relu^2(rb1 @ fcA^T)_chunk @ fc2B_chunk^T
// ---------------------------------------------------------------------------
__global__ __launch_bounds__(256, 2) void mlp_mid_k(
    const u16* __restrict__ rb1, const u16* __restrict__ fcA,
    const u16* __restrict__ fc2B, float* __restrict__ parts)
{
  __shared__ u16 Hs[128 * 128];
  const int t = threadIdx.x, w = t >> 6, l = t & 63;
  const int lr = l & 15, lg = l >> 4;
  const int brow = blockIdx.x << 7;
  const int z = blockIdx.z;
  const int hidOff = (w >> 1) << 6, mOff = (w & 1) << 6;   // hop1 wave layout
  const int mOff2 = (w >> 1) << 6, r2Off = (w & 1) << 6;   // hop2 wave layout
  f32x4 acc2[4][4] = {};
#pragma unroll 1
  for (int cc = 0; cc < 2; ++cc) {
    const int H0 = (z * 2 + cc) << 7;
    bf16x8 rb1F[4][4];
#pragma unroll
    for (int mt = 0; mt < 4; ++mt)
#pragma unroll
      for (int ks = 0; ks < 4; ++ks)
        rb1F[mt][ks] = *(const bf16x8*)(rb1 + (size_t)(brow + mOff + mt * 16 + lr) * 128 + ks * 32 + lg * 8);
    f32x4 acc1[4][4] = {};   // [hn][mt]
#pragma unroll
    for (int hn = 0; hn < 4; ++hn) {
      bf16x8 aF[4];
#pragma unroll
      for (int ks = 0; ks < 4; ++ks)
        aF[ks] = *(const bf16x8*)(fcA + (size_t)(H0 + hidOff + hn * 16 + lr) * 128 + ks * 32 + lg * 8);
#pragma unroll
      for (int mt = 0; mt < 4; ++mt)
#pragma unroll
        for (int ks = 0; ks < 4; ++ks)
          acc1[hn][mt] = __builtin_amdgcn_mfma_f32_16x16x32_bf16(aF[ks], rb1F[mt][ks], acc1[hn][mt], 0, 0, 0);
    }
#pragma unroll
    for (int hn = 0; hn < 4; ++hn)
#pragma unroll
      for (int mt = 0; mt < 4; ++mt) {
        float r0 = acc1[hn][mt][0] > 0.f ? acc1[hn][mt][0] * acc1[hn][mt][0] : 0.f;
        float r1 = acc1[hn][mt][1] > 0.f ? acc1[hn][mt][1] * acc1[hn][mt][1] : 0.f;
        float r2 = acc1[hn][mt][2] > 0.f ? acc1[hn][mt][2] * acc1[hn][mt][2] : 0.f;
        float r3 = acc1[hn][mt][3] > 0.f ? acc1[hn][mt][3] * acc1[hn][mt][3] : 0.f;
        uint2 pk; pk.x = cvtpk(r0, r1); pk.y = cvtpk(r2, r3);
        int m = mOff + mt * 16 + lr;
        int hl = hidOff + hn * 16 + lg * 4;
        int cg = hl >> 3;
        *(uint2*)((char*)Hs + m * 256 + (((cg ^ (m & 7)) << 4) | ((hl & 7) << 1))) = pk;
      }
    __syncthreads();
#pragma unroll
    for (int ks2 = 0; ks2 < 4; ++ks2) {
      bf16x8 hF[4];
#pragma unroll
      for (int mt = 0; mt < 4; ++mt) {
        int m = mOff2 + mt * 16 + lr;
        int hl = ks2 * 32 + lg * 8;
        int cg = hl >> 3;
        hF[mt] = *(const bf16x8*)((const char*)Hs + m * 256 + (((cg ^ (m & 7)) << 4)));
      }
#pragma unroll
      for (int nf = 0; nf < 4; ++nf) {
        bf16x8 bF = *(const bf16x8*)(fc2B + (size_t)(r2Off + nf * 16 + lr) * 8192 + H0 + ks2 * 32 + lg * 8);
#pragma unroll
        for (int mt = 0; mt < 4; ++mt)
          acc2[mt][nf] = __builtin_amdgcn_mfma_f32_16x16x32_bf16(hF[mt], bF, acc2[mt][nf], 0, 0, 0);
      }
    }
    __syncthreads();
  }
  float* P = parts + (size_t)z * 2048 * 128;
#pragma unroll
  for (int mt = 0; mt < 4; ++mt)
#pragma unroll
    for (int nf = 0; nf < 4; ++nf)
#pragma unroll
      for (int j = 0; j < 4; ++j)
        P[(size_t)(brow + mOff2 + mt * 16 + lg * 4 + j) * 128 + r2Off + nf * 16 + lr] = acc2[mt][nf][j];
}

// Sum split-K partials -> bf16 (vectorized: n4 = n/4)
__global__ __launch_bounds__(256) void redcvt_k(const float* __restrict__ parts,
                                                u16* __restrict__ out, int n4, int S)
{
  int i = blockIdx.x * 256 + threadIdx.x;
  if (i >= n4) return;
  float4 s = make_float4(0.f, 0.f, 0.f, 0.f);
  for (int z = 0; z < S; ++z) {
    float4 v = ((const float4*)parts)[(size_t)z * n4 + i];
    s.x += v.x; s.y += v.y; s.z += v.z; s.w += v.w;
  }
  uint2 o; o.x = cvtpk(s.x, s.y); o.y = cvtpk(s.z, s.w);
  ((uint2*)out)[i] = o;
}

// ---------------------------------------------------------------------------
// Fused prep: weight f32->bf16 conversion + attn rmsnorm + value-emb rank GEMM
// ---------------------------------------------------------------------------
struct ConvArgs { const float* s[15]; int off[16]; };

__device__ __forceinline__ void rms_body(const float* __restrict__ xr,
                                         const float* __restrict__ wg,
                                         u16* __restrict__ orow, float eps,
                                         __shared__ float* red)
{
  float v[8]; float ss = 0.f;
#pragma unroll
  for (int i = 0; i < 8; ++i) { v[i] = xr[threadIdx.x + i * 256]; ss += v[i] * v[i]; }
#pragma unroll
  for (int m = 1; m < 64; m <<= 1) ss += __shfl_xor(ss, m);
  if ((threadIdx.x & 63) == 0) red[threadIdx.x >> 6] = ss;
  __syncthreads();
  float tot = red[0] + red[1] + red[2] + red[3];
  float rs = rsqrtf(tot * (1.0f / DIMN) + eps);
#pragma unroll
  for (int i = 0; i < 8; ++i) { int c = threadIdx.x + i * 256; orow[c] = f2bf(v[i] * rs * wg[c]); }
}

__global__ __launch_bounds__(256) void prep_k(ConvArgs a, u16* __restrict__ dst,
                                              const float* __restrict__ x,
                                              const float* __restrict__ anw,
                                              u16* __restrict__ xa,
                                              const int* __restrict__ ids,
                                              const float* __restrict__ emb,
                                              const float* __restrict__ vpB,
                                              u16* __restrict__ t16)
{
  __shared__ float red[4];
  const int b = blockIdx.x;
  if (b < 2792) {
    int i = b * 256 + threadIdx.x;
    if (i >= 714752) return;
    int i8 = i * 8;
    int seg = 0;
#pragma unroll
    for (int k = 1; k < 15; ++k) if (i8 >= a.off[k]) seg = k;
    const float* s = a.s[seg] + (i8 - a.off[seg]);
    float4 f0 = *(const float4*)s, f1 = *(const float4*)(s + 4);
    uint4 o; o.x = cvtpk(f0.x, f0.y); o.y = cvtpk(f0.z, f0.w);
    o.z = cvtpk(f1.x, f1.y); o.w = cvtpk(f1.z, f1.w);
    *(uint4*)(dst + i8) = o;
  } else if (b < 2792 + 2048) {
    int row = b - 2792;
    rms_body(x + (size_t)row * DIMN, anw, xa + (size_t)row * DIMN, 1e-6f, red);
  } else {
    int idx = (b - 4840) * 256 + threadIdx.x;   // 2048*32
    int m = idx >> 5, n = idx & 31;
    int id = ids[m]; id = id < 0 ? 0 : (id > 50256 ? 50256 : id);
    const float* e = emb + (size_t)id * 64;
    const float* wr = vpB + n * 64;
    float s = 0.f;
#pragma unroll
    for (int k = 0; k < 64; ++k) s += e[k] * wr[k];
    t16[idx] = f2bf(s);
  }
}

// rmsnorm (standalone, mlp)
__global__ __launch_bounds__(256) void rmsnorm_k(const float* __restrict__ x,
                                                 const float* __restrict__ wg,
                                                 u16* __restrict__ o, float eps)
{
  __shared__ float red[4];
  int row = blockIdx.x;
  rms_body(x + (size_t)row * DIMN, wg, o + (size_t)row * DIMN, eps, red);
}

// vt[d][t] = bf16(v32[t][d]) via 64x64 LDS tile transpose  [proven]
__global__ __launch_bounds__(256) void vtprep_k(const float* __restrict__ v32, u16* __restrict__ vt)
{
  __shared__ float tile[64][65];
  const int t0 = blockIdx.x << 6;
  const int d0 = blockIdx.y << 6;
  int tr = threadIdx.x >> 4;
  int c4 = threadIdx.x & 15;
#pragma unroll
  for (int i = 0; i < 4; ++i) {
    int row = tr + i * 16;
    float4 v = *(const float4*)(v32 + (size_t)(t0 + row) * 512 + d0 + c4 * 4);
    tile[row][c4 * 4 + 0] = v.x; tile[row][c4 * 4 + 1] = v.y;
    tile[row][c4 * 4 + 2] = v.z; tile[row][c4 * 4 + 3] = v.w;
  }
  __syncthreads();
  int dl = threadIdx.x >> 2;
  int ts = (threadIdx.x & 3) * 16;
  u16* orow = vt + (size_t)(d0 + dl) * 2048 + t0 + ts;
#pragma unroll
  for (int k = 0; k < 16; k += 2) {
    unsigned int pk = cvtpk(tile[ts + k][dl], tile[ts + k + 1][dl]);
    *(unsigned int*)(orow + k) = pk;
  }
}

// ---------------------------------------------------------------------------
// Flash attention: kv-head-shared, no split, double-buffered counted-vmcnt.
// Grid 256 blocks = (kh, 32 q-rows); 4 waves = 4 heads of kh share K/V tiles.
// ---------------------------------------------------------------------------
__device__ __forceinline__ int read_window(const int* wptr){
  int W = *wptr;
  if (W > 65536 || W < 0) { union { int i; float f; } u; u.i = W; W = (int)u.f; }
  if (W < 1) W = 1;
  if (W > SEQT) W = SEQT;
  return W;
}

__global__ __launch_bounds__(256, 2) void attn_k(
    const u16* __restrict__ Q, const u16* __restrict__ Kx, const u16* __restrict__ Vt,
    u16* __restrict__ O, const int* __restrict__ wptr)
{
  __shared__ u16 Ks[2][64 * 128];
  __shared__ u16 Vs[2][128 * 64];
  __shared__ u16 Pl[4][2][16 * 64];
  const int t = threadIdx.x;
  const int w = t >> 6, l = t & 63;
  const int lr = l & 15, lg = l >> 4;
  const int kh = blockIdx.x >> 6, qb = blockIdx.x & 63;  // flat%8 = qb%8 -> XCD spread
  const int h = kh * 4 + w;                              // wave = head
  const int qb0 = qb << 5;
  const int W = read_window(wptr);
  int kstart = qb0 - W + 1;
  if (kstart < 0) kstart = 0;
  kstart &= ~63;
  const int kc_max = (qb0 + 31) & ~63;
  const int nt = ((kc_max - kstart) >> 6) + 1;
  bf16x8 qF[2][4];
#pragma unroll
  for (int g = 0; g < 2; ++g)
#pragma unroll
    for (int ks = 0; ks < 4; ++ks)
      qF[g][ks] = *(const bf16x8*)(Q + (size_t)(qb0 + g * 16 + lr) * DIMN + h * 128 + ks * 32 + lg * 8);
  f32x4 oacc[2][8] = {};
  float lsum[2] = {0.f, 0.f};
  const int swz = (lr & 7) << 4;
  char* PlB0 = (char*)&Pl[w][0][0] + lr * 128;
  char* PlB1 = (char*)&Pl[w][1][0] + lr * 128;

  auto stage = [&](int buf, int kc){
#pragma unroll
    for (int i = 0; i < 4; ++i) {
      int eo = i * 2048 + t * 8;
      int row = eo >> 7, cg = (eo >> 3) & 15;
      gload_lds16(Kx + (size_t)(kc + row) * 512 + kh * 128 + (((cg ^ row) & 15) << 3), &Ks[buf][eo]);
    }
#pragma unroll
    for (int i = 0; i < 4; ++i) {
      int eo = i * 2048 + t * 8;
      int d = eo >> 6, kg = (eo >> 3) & 7;
      gload_lds16(Vt + (size_t)kh * (128 * SEQT) + (size_t)d * SEQT + kc + (((kg ^ d) & 7) << 3), &Vs[buf][eo]);
    }
  };

  stage(0, kstart);
  for (int tt = 0; tt < nt; ++tt) {
    const int kc = kstart + (tt << 6);
    const int nx = (tt + 1 < nt) ? tt + 1 : tt;   // dummy re-stage on last iter
    stage((tt + 1) & 1, kstart + (nx << 6));
    asm volatile("s_waitcnt vmcnt(8)" ::: "memory");   // tile tt landed; tt+1 in flight
    __builtin_amdgcn_sched_barrier(0);
    __builtin_amdgcn_s_barrier();
    const u16* KsC = &Ks[tt & 1][0];
    const u16* VsC = &Vs[tt & 1][0];
    f32x4 sf0[4] = {}, sf1[4] = {};
#pragma unroll
    for (int ks = 0; ks < 4; ++ks)
#pragma unroll
      for (int n = 0; n < 4; ++n) {
        int row = n * 16 + lr, kg = ks * 4 + lg;
        bf16x8 kF = *(const bf16x8*)&KsC[(row << 7) + (((kg ^ row) & 15) << 3)];
        sf0[n] = __builtin_amdgcn_mfma_f32_16x16x32_bf16(kF, qF[0][ks], sf0[n], 0, 0, 0);
        sf1[n] = __builtin_amdgcn_mfma_f32_16x16x32_bf16(kF, qF[1][ks], sf1[n], 0, 0, 0);
      }
#pragma unroll
    for (int g = 0; g < 2; ++g) {
      f32x4* sf = g ? sf1 : sf0;
      char* PlB = g ? PlB1 : PlB0;
      const int qg0 = qb0 + g * 16;
      const int qi = qg0 + lr;
      const bool fullv = ((kc + 63) <= qg0) && ((qg0 + 15 - kc) < W);
      if (fullv) {
#pragma unroll
        for (int n = 0; n < 4; ++n)
#pragma unroll
          for (int j = 0; j < 4; ++j) {
            float p = fexp2(sf[n][j]);
            sf[n][j] = p; lsum[g] += p;
          }
      } else {
#pragma unroll
        for (int n = 0; n < 4; ++n)
#pragma unroll
          for (int j = 0; j < 4; ++j) {
            int kj = kc + n * 16 + lg * 4 + j;
            bool vld = (kj <= qi) && ((qi - kj) < W);
            float p = vld ? fexp2(sf[n][j]) : 0.f;
            sf[n][j] = p; lsum[g] += p;
          }
      }
#pragma unroll
      for (int n = 0; n < 4; ++n) {
        uint2 pk;
        pk.x = cvtpk(sf[n][0], sf[n][1]);
        pk.y = cvtpk(sf[n][2], sf[n][3]);
        *(uint2*)(PlB + ((n * 32 + lg * 8) ^ swz)) = pk;
      }
    }
#pragma unroll
    for (int ks = 0; ks < 2; ++ks) {
      int kgp = ks * 4 + lg;
      bf16x8 pF0 = *(const bf16x8*)(PlB0 + ((kgp * 16) ^ swz));
      bf16x8 pF1 = *(const bf16x8*)(PlB1 + ((kgp * 16) ^ swz));
#pragma unroll
      for (int nd = 0; nd < 8; ++nd) {
        int d = nd * 16 + lr;
        bf16x8 vF = *(const bf16x8*)&VsC[(d << 6) + (((kgp ^ d) & 7) << 3)];
        oacc[0][nd] = __builtin_amdgcn_mfma_f32_16x16x32_bf16(pF0, vF, oacc[0][nd], 0, 0, 0);
        oacc[1][nd] = __builtin_amdgcn_mfma_f32_16x16x32_bf16(pF1, vF, oacc[1][nd], 0, 0, 0);
      }
    }
    __builtin_amdgcn_s_barrier();   // all waves done reading buf before re-stage
  }
#pragma unroll
  for (int g = 0; g < 2; ++g) {
    float ls = lsum[g];
    ls += __shfl_xor(ls, 16);
    ls += __shfl_xor(ls, 32);
    float inv[4];
#pragma unroll
    for (int j = 0; j < 4; ++j) inv[j] = 1.0f / __shfl(ls, lg * 4 + j);
#pragma unroll
    for (int nd = 0; nd < 8; ++nd)
#pragma unroll
      for (int j = 0; j < 4; ++j)
        O[(size_t)(qb0 + g * 16 + lg * 4 + j) * DIMN + h * 128 + nd * 16 + lr] =
            f2bf(oacc[g][nd][j] * inv[j]);
  }
}

// ---------------------------------------------------------------------------
extern "C" void kernel_launch(void* const* d_in, const int* in_sizes, int n_in,
                              void* d_out, int out_size, void* d_ws, size_t ws_size,
                              hipStream_t stream)
{
  (void)in_sizes; (void)n_in; (void)out_size; (void)ws_size;
  const float* x          = (const float*)d_in[0];
  const int*   ids        = (const int*)d_in[1];
  const int*   wptr       = (const int*)d_in[2];
  const float* anw        = (const float*)d_in[3];
  const float* attn_scale = (const float*)d_in[14];
  const float* q_gain     = (const float*)d_in[15];
  const float* vemb       = (const float*)d_in[16];
  const float* vpB        = (const float*)d_in[17];
  const float* mnw        = (const float*)d_in[19];
  const float* mlp_scale  = (const float*)d_in[24];

  char* ws = (char*)d_ws;
  u16* W16 = (u16*)ws;
  static const int WOFF[16] = {0, 524288, 1048576, 1572864, 1638400, 1703936,
                               1769472, 1900544, 2031616, 2555904, 3080192,
                               3096576, 3358720, 4407296, 5455872, 5718016};
  const u16* qkB16   = W16 + WOFF[0];   // 512 x 2048
  const u16* qA16    = W16 + WOFF[2];
  const u16* kvA16   = W16 + WOFF[3];
  const u16* kuvuB16 = W16 + WOFF[4];   // 512 x 256
  const u16* kuA16   = W16 + WOFF[6];
  const u16* vuA16   = W16 + WOFF[7];
  const u16* oB16    = W16 + WOFF[8];
  const u16* oA16    = W16 + WOFF[9];
  const u16* vpA16   = W16 + WOFF[10];
  const u16* fcB16   = W16 + WOFF[11];
  const u16* fcA16   = W16 + WOFF[12];
  const u16* fc2B16  = W16 + WOFF[13];
  const u16* fc2A16  = W16 + WOFF[14];

  u16*   xa16  = (u16*)(ws + 11534336);  // 8MB (norm output, q/kv then mlp)
  u16*   rb1   = (u16*)(ws + 19922944);  // 2MB rank buf
  u16*   z16   = (u16*)(ws + 22020096);  // 1MB kv-latent
  u16*   rb2   = (u16*)(ws + 23068672);  // 2MB ku/vu ranks
  u16*   k16   = (u16*)(ws + 25165824);  // 2MB
  float* v32   = (float*)(ws + 27262976);// 4MB
  u16*   vt16  = (u16*)(ws + 31457280);  // 2MB
  u16*   q16   = (u16*)(ws + 33554432);  // 8MB
  u16*   ao16  = (u16*)(ws + 41943040);  // 8MB
  float* parts = (float*)(ws + 50331648);// <=32MB mlp partials
  u16*   t16   = (u16*)(ws + 83886080);  // 128KB value-emb rank
  float* x2    = (float*)d_out;

  ConvArgs ca;
  const int widx[15] = {4, 6, 5, 7, 8, 10, 9, 11, 12, 13, 18, 20, 21, 22, 23};
  for (int i = 0; i < 15; ++i) ca.s[i] = (const float*)d_in[widx[i]];
  for (int i = 0; i < 16; ++i) ca.off[i] = WOFF[i];

  // fused prep: weight convert + attn rmsnorm + value-emb rank GEMM
  prep_k<<<5096, 256, 0, stream>>>(ca, W16, x, anw, xa16, ids, vemb, vpB, t16);

  // fused hop1: rb1 = xa @ [qB;kvB].T  (N=512, no split, direct bf16)
  gemm_nt<64, 1><<<dim3(16, 4, 1), 256, 0, stream>>>(xa16, qkB16, rb1, 2048, 512, 2048, 2048, nullptr, nullptr, nullptr, nullptr);
  // q = rope(rms(rb1[:, :256] @ qA.T)) * gain*scale  [validated R12]
  hop2q_k<<<dim3(16, 16), 256, 0, stream>>>(rb1, qA16, q16, q_gain);
  // z = rb1[:, 256:] @ kvA.T
  gemm_nt<64, 1><<<dim3(16, 2, 1), 256, 0, stream>>>(rb1 + 256, kvA16, z16, 2048, 256, 256, 512, nullptr, nullptr, nullptr, nullptr);
  // fused ku/vu hop1: z @ [kuB;vuB].T  (N=512)
  gemm_nt<64, 1><<<dim3(16, 4, 1), 256, 0, stream>>>(z16, kuvuB16, rb2, 2048, 512, 256, 256, nullptr, nullptr, nullptr, nullptr);
  // k = rms(rb2[:, :256] @ kuA.T) fused epilogue  [validated R9]
  hop2k_k<<<dim3(16, 4), 256, 0, stream>>>(rb2, kuA16, k16);
  // v = rb2[:, 256:] @ vuA.T + t16 @ vpA.T   (DUAL, f32 out)  [proven]
  gemm_nt<64, 0, true><<<dim3(16, 4, 1), 256, 0, stream>>>(rb2 + 256, vuA16, v32, 2048, 512, 256, 512, nullptr, nullptr, t16, vpA16);
  vtprep_k<<<dim3(32, 8), 256, 0, stream>>>(v32, vt16);
  // attention (single pass, direct bf16 out)
  attn_k<<<256, 256, 0, stream>>>(q16, k16, vt16, ao16, wptr);
  // o-proj: hop1 no split (direct bf16), hop2 fused with residual (x + sc*o)
  gemm_nt<64, 1><<<dim3(16, 2, 1), 256, 0, stream>>>(ao16, oB16, rb1, 2048, 256, 2048, 2048, nullptr, nullptr, nullptr, nullptr);
  gemm_nt<64, 4><<<dim3(16, 16, 1), 256, 0, stream>>>(rb1, oA16, x2, 2048, 2048, 256, 256, x, attn_scale, nullptr, nullptr);
  // mlp
  rmsnorm_k<<<2048, 256, 0, stream>>>(x2, mnw, xa16, 1e-6f);
  gemm_nt<64, 0><<<dim3(16, 1, 8), 256, 0, stream>>>(xa16, fcB16, parts, 2048, 128, 2048, 2048, nullptr, nullptr, nullptr, nullptr);
  redcvt_k<<<256, 256, 0, stream>>>(parts, rb1, 65536, 8);
  mlp_mid_k<<<dim3(16, 1, 32), 256, 0, stream>>>(rb1, fcA16, fc2B16, parts);
  redcvt_k<<<256, 256, 0, stream>>>(parts, rb1, 65536, 32);
  gemm_nt<64, 4><<<dim3(16, 16, 1), 256, 0, stream>>>(rb1, fc2A16, x2, 2048, 2048, 128, 128, x2, mlp_scale, nullptr, nullptr);
}

// Round 14
// 202.426 us; speedup vs baseline: 1.1699x; 1.1699x over previous
//
#include <hip/hip_runtime.h>
#include <cstdint>
#include <cstddef>

typedef unsigned short u16;
typedef __attribute__((ext_vector_type(4))) float f32x4;
typedef __attribute__((ext_vector_type(8))) short bf16x8;

#define SEQT 2048
#define DIMN 2048

__device__ __forceinline__ float bf2f(u16 h){
  union { unsigned int u; float f; } v; v.u = ((unsigned int)h) << 16; return v.f;
}
__device__ __forceinline__ u16 f2bf(float f){
  union { float f; unsigned int u; } v; v.f = f;
  unsigned int r = v.u + 0x7fffu + ((v.u >> 16) & 1u);
  return (u16)(r >> 16);
}
__device__ __forceinline__ float fexp2(float x){
  float r;
  asm("v_exp_f32 %0, %1" : "=v"(r) : "v"(x));
  return r;
}
__device__ __forceinline__ unsigned int cvtpk(float lo, float hi){
  unsigned int r;
  asm("v_cvt_pk_bf16_f32 %0, %1, %2" : "=v"(r) : "v"(lo), "v"(hi));
  return r;
}

typedef const __attribute__((address_space(1))) unsigned int* gas1_t;
typedef __attribute__((address_space(3))) unsigned int* las3_t;
__device__ __forceinline__ void gload_lds16(const void* g, void* l){
  __builtin_amdgcn_global_load_lds((gas1_t)g, (las3_t)l, 16, 0, 0);
}

// ---------------------------------------------------------------------------
// Generic NT GEMM: C[m,n] = sum_k A[m,k]*B[n,k], A:(M,lda) bf16, B:(N,K) bf16.
// BM=128, BN=128; 256 threads = 4 waves 2x2, each 64x64 (4x4 frags).
// EPI: 0 f32 store (+z-offset, split-K), 1 bf16 store, 4 f32 = Xres+SC[col]*acc
// DUAL: adds a K2=32 tail  acc += A2 @ B2^T  (reg-direct, no LDS).
// NOTE (R13 lesson): for K=2048 skinny-N, keep split-K >= 4 — the serial
// K-loop latency at low block counts costs far more than the redcvt pass.
// ---------------------------------------------------------------------------
template<int BK, int EPI, bool DUAL = false>
__global__ __launch_bounds__(256, 2) void gemm_nt(
    const u16* __restrict__ A, const u16* __restrict__ B, void* __restrict__ Cv,
    int M, int N, int K, int lda, const float* __restrict__ Xres,
    const float* __restrict__ SC, const u16* __restrict__ A2,
    const u16* __restrict__ B2)
{
  __shared__ u16 As[128 * BK];
  __shared__ u16 Bs[128 * BK];
  constexpr int ITER = (128 * BK) / 2048;
  constexpr int GM = BK / 8 - 1;
  const int t = threadIdx.x;
  const int w = t >> 6, l = t & 63;
  const int lr = l & 15, lg = l >> 4;
  const int brow = blockIdx.x << 7, bcol = blockIdx.y << 7;
  const int wr = (w >> 1) << 6, wc = (w & 1) << 6;
  const int Kc = K / gridDim.z;
  const int kbeg = blockIdx.z * Kc;
  const int kend = kbeg + Kc;
  f32x4 acc[4][4] = {};
  for (int k0 = kbeg; k0 < kend; k0 += BK) {
    __syncthreads();
#pragma unroll
    for (int i = 0; i < ITER; ++i) {
      int eo = i * 2048 + t * 8;
      int row = eo / BK;
      int cg = (eo & (BK - 1)) >> 3;
      int scol = ((cg ^ row) & GM) << 3;       // pre-swizzled global source
      gload_lds16(A + (size_t)(brow + row) * lda + k0 + scol, &As[eo]);
      gload_lds16(B + (size_t)(bcol + row) * K + k0 + scol, &Bs[eo]);
    }
    __syncthreads();
#pragma unroll
    for (int ks = 0; ks < BK / 32; ++ks) {
      bf16x8 aF[4], bF[4];
#pragma unroll
      for (int m = 0; m < 4; ++m) {
        int row = wr + m * 16 + lr;
        int kg = ks * 4 + lg;
        aF[m] = *(const bf16x8*)&As[row * BK + (((kg ^ row) & GM) << 3)];
      }
#pragma unroll
      for (int n = 0; n < 4; ++n) {
        int row = wc + n * 16 + lr;
        int kg = ks * 4 + lg;
        bF[n] = *(const bf16x8*)&Bs[row * BK + (((kg ^ row) & GM) << 3)];
      }
#pragma unroll
      for (int m = 0; m < 4; ++m)
#pragma unroll
        for (int n = 0; n < 4; ++n)
          acc[m][n] = __builtin_amdgcn_mfma_f32_16x16x32_bf16(aF[m], bF[n], acc[m][n], 0, 0, 0);
    }
  }
  if constexpr (DUAL) {
    bf16x8 aF2[4], bF2[4];
#pragma unroll
    for (int m = 0; m < 4; ++m)
      aF2[m] = *(const bf16x8*)(A2 + (size_t)(brow + wr + m * 16 + lr) * 32 + lg * 8);
#pragma unroll
    for (int n = 0; n < 4; ++n)
      bF2[n] = *(const bf16x8*)(B2 + (size_t)(bcol + wc + n * 16 + lr) * 32 + lg * 8);
#pragma unroll
    for (int m = 0; m < 4; ++m)
#pragma unroll
      for (int n = 0; n < 4; ++n)
        acc[m][n] = __builtin_amdgcn_mfma_f32_16x16x32_bf16(aF2[m], bF2[n], acc[m][n], 0, 0, 0);
  }
  const size_t zoff = (size_t)blockIdx.z * (size_t)M * (size_t)N;
#pragma unroll
  for (int m = 0; m < 4; ++m)
#pragma unroll
    for (int n = 0; n < 4; ++n)
#pragma unroll
      for (int j = 0; j < 4; ++j) {
        int row = brow + wr + m * 16 + lg * 4 + j;
        int col = bcol + wc + n * 16 + lr;
        float v = acc[m][n][j];
        if constexpr (EPI == 0) ((float*)Cv)[zoff + (size_t)row * N + col] = v;
        else if constexpr (EPI == 1) ((u16*)Cv)[(size_t)row * N + col] = f2bf(v);
        else {
          float xo = Xres[(size_t)row * N + col];
          ((float*)Cv)[(size_t)row * N + col] = xo + SC[col] * v;
        }
      }
}

// ---------------------------------------------------------------------------
// hop2k: k16 = rms_HEPS_per_head( rb2[:, :256] @ kuA^T ).  4x1 wave layout:
// each wave owns 32 rows x 128 cols (one kv-head per blockIdx.y) so the
// per-row sum-of-squares is ENTIRELY intra-wave.  [VALIDATED R9]
// ---------------------------------------------------------------------------
__global__ __launch_bounds__(256, 2) void hop2k_k(
    const u16* __restrict__ rb2, const u16* __restrict__ kuA,
    u16* __restrict__ k16)
{
  __shared__ u16 As[128 * 64];
  __shared__ u16 Bs[128 * 64];
  const int t = threadIdx.x, w = t >> 6, l = t & 63;
  const int lr = l & 15, lg = l >> 4;
  const int brow = blockIdx.x << 7;
  const int bcol = blockIdx.y << 7;            // one kv-head per y
  const u16* B = kuA + (size_t)bcol * 256;
  const int wr2 = w << 5;                      // wave: 32 rows x 128 cols
  f32x4 acc[2][8] = {};
  for (int k0 = 0; k0 < 256; k0 += 64) {
    __syncthreads();
#pragma unroll
    for (int i = 0; i < 4; ++i) {
      int eo = i * 2048 + t * 8;
      int row = eo >> 6, cg = (eo >> 3) & 7;
      int scol = ((cg ^ row) & 7) << 3;
      gload_lds16(rb2 + (size_t)(brow + row) * 512 + k0 + scol, &As[eo]);
      gload_lds16(B + (size_t)row * 256 + k0 + scol, &Bs[eo]);
    }
    __syncthreads();
#pragma unroll
    for (int ks = 0; ks < 2; ++ks) {
      bf16x8 aF[2], bF[8];
#pragma unroll
      for (int m = 0; m < 2; ++m) {
        int row = wr2 + m * 16 + lr, kg = ks * 4 + lg;
        aF[m] = *(const bf16x8*)&As[(row << 6) + (((kg ^ row) & 7) << 3)];
      }
#pragma unroll
      for (int n = 0; n < 8; ++n) {
        int row = n * 16 + lr, kg = ks * 4 + lg;
        bF[n] = *(const bf16x8*)&Bs[(row << 6) + (((kg ^ row) & 7) << 3)];
      }
#pragma unroll
      for (int m = 0; m < 2; ++m)
#pragma unroll
        for (int n = 0; n < 8; ++n)
          acc[m][n] = __builtin_amdgcn_mfma_f32_16x16x32_bf16(aF[m], bF[n], acc[m][n], 0, 0, 0);
    }
  }
#pragma unroll
  for (int m = 0; m < 2; ++m)
#pragma unroll
    for (int j = 0; j < 4; ++j) {
      float s = 0.f;
#pragma unroll
      for (int n = 0; n < 8; ++n) { float v = acc[m][n][j]; s += v * v; }
#pragma unroll
      for (int mm = 1; mm < 16; mm <<= 1) s += __shfl_xor(s, mm);
      float rs = rsqrtf(s * (1.0f / 128.0f) + 1.1920929e-07f);
      int row = brow + wr2 + m * 16 + lg * 4 + j;
#pragma unroll
      for (int n = 0; n < 8; ++n)
        k16[(size_t)row * 512 + bcol + n * 16 + lr] = f2bf(acc[m][n][j] * rs);
    }
}

// ---------------------------------------------------------------------------
// hop2q [VALIDATED R12]: q16 = gain*scale*rope( rms_HEPS( rb1[:, :256]
// @ qA^T ) ) per head.  4x1 layout; one head per blockIdx.y.
// ---------------------------------------------------------------------------
__global__ __launch_bounds__(256, 2) void hop2q_k(
    const u16* __restrict__ rb1, const u16* __restrict__ qA,
    u16* __restrict__ q16, const float* __restrict__ gain)
{
  __shared__ u16 As[128 * 64];
  __shared__ u16 Bs[128 * 64];
  const int t = threadIdx.x, w = t >> 6, l = t & 63;
  const int lr = l & 15, lg = l >> 4;
  const int brow = blockIdx.x << 7;
  const int hh = blockIdx.y;                   // head
  const u16* B = qA + ((size_t)hh << 7) * 256;
  const int wr2 = w << 5;
  f32x4 acc[2][8] = {};
  for (int k0 = 0; k0 < 256; k0 += 64) {
    __syncthreads();
#pragma unroll
    for (int i = 0; i < 4; ++i) {
      int eo = i * 2048 + t * 8;
      int row = eo >> 6, cg = (eo >> 3) & 7;
      int scol = ((cg ^ row) & 7) << 3;
      gload_lds16(rb1 + (size_t)(brow + row) * 512 + k0 + scol, &As[eo]);
      gload_lds16(B + (size_t)row * 256 + k0 + scol, &Bs[eo]);
    }
    __syncthreads();
#pragma unroll
    for (int ks = 0; ks < 2; ++ks) {
      bf16x8 aF[2], bF[8];
#pragma unroll
      for (int m = 0; m < 2; ++m) {
        int row = wr2 + m * 16 + lr, kg = ks * 4 + lg;
        aF[m] = *(const bf16x8*)&As[(row << 6) + (((kg ^ row) & 7) << 3)];
      }
#pragma unroll
      for (int n = 0; n < 8; ++n) {
        int row = n * 16 + lr, kg = ks * 4 + lg;
        bF[n] = *(const bf16x8*)&Bs[(row << 6) + (((kg ^ row) & 7) << 3)];
      }
#pragma unroll
      for (int m = 0; m < 2; ++m)
#pragma unroll
        for (int n = 0; n < 8; ++n)
          acc[m][n] = __builtin_amdgcn_mfma_f32_16x16x32_bf16(aF[m], bF[n], acc[m][n], 0, 0, 0);
    }
  }
  const float gm = gain[hh] * 0.08838834764831845f * 1.4426950408889634f; // 1/sqrt(128)*log2e
#pragma unroll
  for (int m = 0; m < 2; ++m)
#pragma unroll
    for (int j = 0; j < 4; ++j) {
      float s = 0.f;
#pragma unroll
      for (int n = 0; n < 8; ++n) { float v = acc[m][n][j]; s += v * v; }
#pragma unroll
      for (int mm = 1; mm < 16; mm <<= 1) s += __shfl_xor(s, mm);
      float rs = rsqrtf(s * (1.0f / 128.0f) + 1.1920929e-07f) * gm;
      int row = brow + wr2 + m * 16 + lg * 4 + j;   // token position
#pragma unroll
      for (int n = 0; n < 2; ++n) {
        float fr = __expf(-(float)(n * 16 + lr) * 0.28782313662425574f); // ln(1e4)/32
        float f = (float)row * fr;
        float c = cosf(f), sn = sinf(f);
        float a1 = acc[m][n][j], a2 = acc[m][n + 2][j];
        acc[m][n][j] = a1 * c + a2 * sn;
        acc[m][n + 2][j] = a2 * c - a1 * sn;
      }
#pragma unroll
      for (int n = 0; n < 8; ++n)
        q16[(size_t)row * 2048 + (hh << 7) + n * 16 + lr] = f2bf(acc[m][n][j] * rs);
    }
}

// ---------------------------------------------------------------------------
// Fused MLP middle: parts[z] = relu^2(rb1 @ fcA^T)_chunk @ fc2B_chunk^T
// ---------------------------------------------------------------------------
__global__ __launch_bounds__(256, 2) void mlp_mid_k(
    const u16* __restrict__ rb1, const u16* __restrict__ fcA,
    const u16* __restrict__ fc2B, float* __restrict__ parts)
{
  __shared__ u16 Hs[128 * 128];
  const int t = threadIdx.x, w = t >> 6, l = t & 63;
  const int lr = l & 15, lg = l >> 4;
  const int brow = blockIdx.x << 7;
  const int z = blockIdx.z;
  const int hidOff = (w >> 1) << 6, mOff = (w & 1) << 6;   // hop1 wave layout
  const int mOff2 = (w >> 1) << 6, r2Off = (w & 1) << 6;   // hop2 wave layout
  f32x4 acc2[4][4] = {};
#pragma unroll 1
  for (int cc = 0; cc < 2; ++cc) {
    const int H0 = (z * 2 + cc) << 7;
    bf16x8 rb1F[4][4];
#pragma unroll
    for (int mt = 0; mt < 4; ++mt)
#pragma unroll
      for (int ks = 0; ks < 4; ++ks)
        rb1F[mt][ks] = *(const bf16x8*)(rb1 + (size_t)(brow + mOff + mt * 16 + lr) * 128 + ks * 32 + lg * 8);
    f32x4 acc1[4][4] = {};   // [hn][mt]
#pragma unroll
    for (int hn = 0; hn < 4; ++hn) {
      bf16x8 aF[4];
#pragma unroll
      for (int ks = 0; ks < 4; ++ks)
        aF[ks] = *(const bf16x8*)(fcA + (size_t)(H0 + hidOff + hn * 16 + lr) * 128 + ks * 32 + lg * 8);
#pragma unroll
      for (int mt = 0; mt < 4; ++mt)
#pragma unroll
        for (int ks = 0; ks < 4; ++ks)
          acc1[hn][mt] = __builtin_amdgcn_mfma_f32_16x16x32_bf16(aF[ks], rb1F[mt][ks], acc1[hn][mt], 0, 0, 0);
    }
#pragma unroll
    for (int hn = 0; hn < 4; ++hn)
#pragma unroll
      for (int mt = 0; mt < 4; ++mt) {
        float r0 = acc1[hn][mt][0] > 0.f ? acc1[hn][mt][0] * acc1[hn][mt][0] : 0.f;
        float r1 = acc1[hn][mt][1] > 0.f ? acc1[hn][mt][1] * acc1[hn][mt][1] : 0.f;
        float r2 = acc1[hn][mt][2] > 0.f ? acc1[hn][mt][2] * acc1[hn][mt][2] : 0.f;
        float r3 = acc1[hn][mt][3] > 0.f ? acc1[hn][mt][3] * acc1[hn][mt][3] : 0.f;
        uint2 pk; pk.x = cvtpk(r0, r1); pk.y = cvtpk(r2, r3);
        int m = mOff + mt * 16 + lr;
        int hl = hidOff + hn * 16 + lg * 4;
        int cg = hl >> 3;
        *(uint2*)((char*)Hs + m * 256 + (((cg ^ (m & 7)) << 4) | ((hl & 7) << 1))) = pk;
      }
    __syncthreads();
#pragma unroll
    for (int ks2 = 0; ks2 < 4; ++ks2) {
      bf16x8 hF[4];
#pragma unroll
      for (int mt = 0; mt < 4; ++mt) {
        int m = mOff2 + mt * 16 + lr;
        int hl = ks2 * 32 + lg * 8;
        int cg = hl >> 3;
        hF[mt] = *(const bf16x8*)((const char*)Hs + m * 256 + (((cg ^ (m & 7)) << 4)));
      }
#pragma unroll
      for (int nf = 0; nf < 4; ++nf) {
        bf16x8 bF = *(const bf16x8*)(fc2B + (size_t)(r2Off + nf * 16 + lr) * 8192 + H0 + ks2 * 32 + lg * 8);
#pragma unroll
        for (int mt = 0; mt < 4; ++mt)
          acc2[mt][nf] = __builtin_amdgcn_mfma_f32_16x16x32_bf16(hF[mt], bF, acc2[mt][nf], 0, 0, 0);
      }
    }
    __syncthreads();
  }
  float* P = parts + (size_t)z * 2048 * 128;
#pragma unroll
  for (int mt = 0; mt < 4; ++mt)
#pragma unroll
    for (int nf = 0; nf < 4; ++nf)
#pragma unroll
      for (int j = 0; j < 4; ++j)
        P[(size_t)(brow + mOff2 + mt * 16 + lg * 4 + j) * 128 + r2Off + nf * 16 + lr] = acc2[mt][nf][j];
}

// Sum split-K partials -> bf16 (vectorized: n4 = n/4)
__global__ __launch_bounds__(256) void redcvt_k(const float* __restrict__ parts,
                                                u16* __restrict__ out, int n4, int S)
{
  int i = blockIdx.x * 256 + threadIdx.x;
  if (i >= n4) return;
  float4 s = make_float4(0.f, 0.f, 0.f, 0.f);
  for (int z = 0; z < S; ++z) {
    float4 v = ((const float4*)parts)[(size_t)z * n4 + i];
    s.x += v.x; s.y += v.y; s.z += v.z; s.w += v.w;
  }
  uint2 o; o.x = cvtpk(s.x, s.y); o.y = cvtpk(s.z, s.w);
  ((uint2*)out)[i] = o;
}

// ---------------------------------------------------------------------------
// Fused prep: weight f32->bf16 conversion + attn rmsnorm + value-emb rank GEMM
// ---------------------------------------------------------------------------
struct ConvArgs { const float* s[15]; int off[16]; };

__device__ __forceinline__ void rms_body(const float* __restrict__ xr,
                                         const float* __restrict__ wg,
                                         u16* __restrict__ orow, float eps,
                                         __shared__ float* red)
{
  float v[8]; float ss = 0.f;
#pragma unroll
  for (int i = 0; i < 8; ++i) { v[i] = xr[threadIdx.x + i * 256]; ss += v[i] * v[i]; }
#pragma unroll
  for (int m = 1; m < 64; m <<= 1) ss += __shfl_xor(ss, m);
  if ((threadIdx.x & 63) == 0) red[threadIdx.x >> 6] = ss;
  __syncthreads();
  float tot = red[0] + red[1] + red[2] + red[3];
  float rs = rsqrtf(tot * (1.0f / DIMN) + eps);
#pragma unroll
  for (int i = 0; i < 8; ++i) { int c = threadIdx.x + i * 256; orow[c] = f2bf(v[i] * rs * wg[c]); }
}

__global__ __launch_bounds__(256) void prep_k(ConvArgs a, u16* __restrict__ dst,
                                              const float* __restrict__ x,
                                              const float* __restrict__ anw,
                                              u16* __restrict__ xa,
                                              const int* __restrict__ ids,
                                              const float* __restrict__ emb,
                                              const float* __restrict__ vpB,
                                              u16* __restrict__ t16)
{
  __shared__ float red[4];
  const int b = blockIdx.x;
  if (b < 2792) {
    int i = b * 256 + threadIdx.x;
    if (i >= 714752) return;
    int i8 = i * 8;
    int seg = 0;
#pragma unroll
    for (int k = 1; k < 15; ++k) if (i8 >= a.off[k]) seg = k;
    const float* s = a.s[seg] + (i8 - a.off[seg]);
    float4 f0 = *(const float4*)s, f1 = *(const float4*)(s + 4);
    uint4 o; o.x = cvtpk(f0.x, f0.y); o.y = cvtpk(f0.z, f0.w);
    o.z = cvtpk(f1.x, f1.y); o.w = cvtpk(f1.z, f1.w);
    *(uint4*)(dst + i8) = o;
  } else if (b < 2792 + 2048) {
    int row = b - 2792;
    rms_body(x + (size_t)row * DIMN, anw, xa + (size_t)row * DIMN, 1e-6f, red);
  } else {
    int idx = (b - 4840) * 256 + threadIdx.x;   // 2048*32
    int m = idx >> 5, n = idx & 31;
    int id = ids[m]; id = id < 0 ? 0 : (id > 50256 ? 50256 : id);
    const float* e = emb + (size_t)id * 64;
    const float* wr = vpB + n * 64;
    float s = 0.f;
#pragma unroll
    for (int k = 0; k < 64; ++k) s += e[k] * wr[k];
    t16[idx] = f2bf(s);
  }
}

// rmsnorm (standalone, mlp)
__global__ __launch_bounds__(256) void rmsnorm_k(const float* __restrict__ x,
                                                 const float* __restrict__ wg,
                                                 u16* __restrict__ o, float eps)
{
  __shared__ float red[4];
  int row = blockIdx.x;
  rms_body(x + (size_t)row * DIMN, wg, o + (size_t)row * DIMN, eps, red);
}

// vt[d][t] = bf16(v32[t][d]) via 64x64 LDS tile transpose  [proven]
__global__ __launch_bounds__(256) void vtprep_k(const float* __restrict__ v32, u16* __restrict__ vt)
{
  __shared__ float tile[64][65];
  const int t0 = blockIdx.x << 6;
  const int d0 = blockIdx.y << 6;
  int tr = threadIdx.x >> 4;
  int c4 = threadIdx.x & 15;
#pragma unroll
  for (int i = 0; i < 4; ++i) {
    int row = tr + i * 16;
    float4 v = *(const float4*)(v32 + (size_t)(t0 + row) * 512 + d0 + c4 * 4);
    tile[row][c4 * 4 + 0] = v.x; tile[row][c4 * 4 + 1] = v.y;
    tile[row][c4 * 4 + 2] = v.z; tile[row][c4 * 4 + 3] = v.w;
  }
  __syncthreads();
  int dl = threadIdx.x >> 2;
  int ts = (threadIdx.x & 3) * 16;
  u16* orow = vt + (size_t)(d0 + dl) * 2048 + t0 + ts;
#pragma unroll
  for (int k = 0; k < 16; k += 2) {
    unsigned int pk = cvtpk(tile[ts + k][dl], tile[ts + k + 1][dl]);
    *(unsigned int*)(orow + k) = pk;
  }
}

// ---------------------------------------------------------------------------
// Flash attention: kv-head-shared, no split, double-buffered counted-vmcnt.
// Grid 256 blocks = (kh, 32 q-rows); 4 waves = 4 heads of kh share K/V tiles.
// ---------------------------------------------------------------------------
__device__ __forceinline__ int read_window(const int* wptr){
  int W = *wptr;
  if (W > 65536 || W < 0) { union { int i; float f; } u; u.i = W; W = (int)u.f; }
  if (W < 1) W = 1;
  if (W > SEQT) W = SEQT;
  return W;
}

__global__ __launch_bounds__(256, 2) void attn_k(
    const u16* __restrict__ Q, const u16* __restrict__ Kx, const u16* __restrict__ Vt,
    u16* __restrict__ O, const int* __restrict__ wptr)
{
  __shared__ u16 Ks[2][64 * 128];
  __shared__ u16 Vs[2][128 * 64];
  __shared__ u16 Pl[4][2][16 * 64];
  const int t = threadIdx.x;
  const int w = t >> 6, l = t & 63;
  const int lr = l & 15, lg = l >> 4;
  const int kh = blockIdx.x >> 6, qb = blockIdx.x & 63;  // flat%8 = qb%8 -> XCD spread
  const int h = kh * 4 + w;                              // wave = head
  const int qb0 = qb << 5;
  const int W = read_window(wptr);
  int kstart = qb0 - W + 1;
  if (kstart < 0) kstart = 0;
  kstart &= ~63;
  const int kc_max = (qb0 + 31) & ~63;
  const int nt = ((kc_max - kstart) >> 6) + 1;
  bf16x8 qF[2][4];
#pragma unroll
  for (int g = 0; g < 2; ++g)
#pragma unroll
    for (int ks = 0; ks < 4; ++ks)
      qF[g][ks] = *(const bf16x8*)(Q + (size_t)(qb0 + g * 16 + lr) * DIMN + h * 128 + ks * 32 + lg * 8);
  f32x4 oacc[2][8] = {};
  float lsum[2] = {0.f, 0.f};
  const int swz = (lr & 7) << 4;
  char* PlB0 = (char*)&Pl[w][0][0] + lr * 128;
  char* PlB1 = (char*)&Pl[w][1][0] + lr * 128;

  auto stage = [&](int buf, int kc){
#pragma unroll
    for (int i = 0; i < 4; ++i) {
      int eo = i * 2048 + t * 8;
      int row = eo >> 7, cg = (eo >> 3) & 15;
      gload_lds16(Kx + (size_t)(kc + row) * 512 + kh * 128 + (((cg ^ row) & 15) << 3), &Ks[buf][eo]);
    }
#pragma unroll
    for (int i = 0; i < 4; ++i) {
      int eo = i * 2048 + t * 8;
      int d = eo >> 6, kg = (eo >> 3) & 7;
      gload_lds16(Vt + (size_t)kh * (128 * SEQT) + (size_t)d * SEQT + kc + (((kg ^ d) & 7) << 3), &Vs[buf][eo]);
    }
  };

  stage(0, kstart);
  for (int tt = 0; tt < nt; ++tt) {
    const int kc = kstart + (tt << 6);
    const int nx = (tt + 1 < nt) ? tt + 1 : tt;   // dummy re-stage on last iter
    stage((tt + 1) & 1, kstart + (nx << 6));
    asm volatile("s_waitcnt vmcnt(8)" ::: "memory");   // tile tt landed; tt+1 in flight
    __builtin_amdgcn_sched_barrier(0);
    __builtin_amdgcn_s_barrier();
    const u16* KsC = &Ks[tt & 1][0];
    const u16* VsC = &Vs[tt & 1][0];
    f32x4 sf0[4] = {}, sf1[4] = {};
#pragma unroll
    for (int ks = 0; ks < 4; ++ks)
#pragma unroll
      for (int n = 0; n < 4; ++n) {
        int row = n * 16 + lr, kg = ks * 4 + lg;
        bf16x8 kF = *(const bf16x8*)&KsC[(row << 7) + (((kg ^ row) & 15) << 3)];
        sf0[n] = __builtin_amdgcn_mfma_f32_16x16x32_bf16(kF, qF[0][ks], sf0[n], 0, 0, 0);
        sf1[n] = __builtin_amdgcn_mfma_f32_16x16x32_bf16(kF, qF[1][ks], sf1[n], 0, 0, 0);
      }
#pragma unroll
    for (int g = 0; g < 2; ++g) {
      f32x4* sf = g ? sf1 : sf0;
      char* PlB = g ? PlB1 : PlB0;
      const int qg0 = qb0 + g * 16;
      const int qi = qg0 + lr;
      const bool fullv = ((kc + 63) <= qg0) && ((qg0 + 15 - kc) < W);
      if (fullv) {
#pragma unroll
        for (int n = 0; n < 4; ++n)
#pragma unroll
          for (int j = 0; j < 4; ++j) {
            float p = fexp2(sf[n][j]);
            sf[n][j] = p; lsum[g] += p;
          }
      } else {
#pragma unroll
        for (int n = 0; n < 4; ++n)
#pragma unroll
          for (int j = 0; j < 4; ++j) {
            int kj = kc + n * 16 + lg * 4 + j;
            bool vld = (kj <= qi) && ((qi - kj) < W);
            float p = vld ? fexp2(sf[n][j]) : 0.f;
            sf[n][j] = p; lsum[g] += p;
          }
      }
#pragma unroll
      for (int n = 0; n < 4; ++n) {
        uint2 pk;
        pk.x = cvtpk(sf[n][0], sf[n][1]);
        pk.y = cvtpk(sf[n][2], sf[n][3]);
        *(uint2*)(PlB + ((n * 32 + lg * 8) ^ swz)) = pk;
      }
    }
#pragma unroll
    for (int ks = 0; ks < 2; ++ks) {
      int kgp = ks * 4 + lg;
      bf16x8 pF0 = *(const bf16x8*)(PlB0 + ((kgp * 16) ^ swz));
      bf16x8 pF1 = *(const bf16x8*)(PlB1 + ((kgp * 16) ^ swz));
#pragma unroll
      for (int nd = 0; nd < 8; ++nd) {
        int d = nd * 16 + lr;
        bf16x8 vF = *(const bf16x8*)&VsC[(d << 6) + (((kgp ^ d) & 7) << 3)];
        oacc[0][nd] = __builtin_amdgcn_mfma_f32_16x16x32_bf16(pF0, vF, oacc[0][nd], 0, 0, 0);
        oacc[1][nd] = __builtin_amdgcn_mfma_f32_16x16x32_bf16(pF1, vF, oacc[1][nd], 0, 0, 0);
      }
    }
    __builtin_amdgcn_s_barrier();   // all waves done reading buf before re-stage
  }
#pragma unroll
  for (int g = 0; g < 2; ++g) {
    float ls = lsum[g];
    ls += __shfl_xor(ls, 16);
    ls += __shfl_xor(ls, 32);
    float inv[4];
#pragma unroll
    for (int j = 0; j < 4; ++j) inv[j] = 1.0f / __shfl(ls, lg * 4 + j);
#pragma unroll
    for (int nd = 0; nd < 8; ++nd)
#pragma unroll
      for (int j = 0; j < 4; ++j)
        O[(size_t)(qb0 + g * 16 + lg * 4 + j) * DIMN + h * 128 + nd * 16 + lr] =
            f2bf(oacc[g][nd][j] * inv[j]);
  }
}

// ---------------------------------------------------------------------------
extern "C" void kernel_launch(void* const* d_in, const int* in_sizes, int n_in,
                              void* d_out, int out_size, void* d_ws, size_t ws_size,
                              hipStream_t stream)
{
  (void)in_sizes; (void)n_in; (void)out_size; (void)ws_size;
  const float* x          = (const float*)d_in[0];
  const int*   ids        = (const int*)d_in[1];
  const int*   wptr       = (const int*)d_in[2];
  const float* anw        = (const float*)d_in[3];
  const float* attn_scale = (const float*)d_in[14];
  const float* q_gain     = (const float*)d_in[15];
  const float* vemb       = (const float*)d_in[16];
  const float* vpB        = (const float*)d_in[17];
  const float* mnw        = (const float*)d_in[19];
  const float* mlp_scale  = (const float*)d_in[24];

  char* ws = (char*)d_ws;
  u16* W16 = (u16*)ws;
  static const int WOFF[16] = {0, 524288, 1048576, 1572864, 1638400, 1703936,
                               1769472, 1900544, 2031616, 2555904, 3080192,
                               3096576, 3358720, 4407296, 5455872, 5718016};
  const u16* qkB16   = W16 + WOFF[0];   // 512 x 2048
  const u16* qA16    = W16 + WOFF[2];
  const u16* kvA16   = W16 + WOFF[3];
  const u16* kuvuB16 = W16 + WOFF[4];   // 512 x 256
  const u16* kuA16   = W16 + WOFF[6];
  const u16* vuA16   = W16 + WOFF[7];
  const u16* oB16    = W16 + WOFF[8];
  const u16* oA16    = W16 + WOFF[9];
  const u16* vpA16   = W16 + WOFF[10];
  const u16* fcB16   = W16 + WOFF[11];
  const u16* fcA16   = W16 + WOFF[12];
  const u16* fc2B16  = W16 + WOFF[13];
  const u16* fc2A16  = W16 + WOFF[14];

  u16*   xa16  = (u16*)(ws + 11534336);  // 8MB (norm output, q/kv then mlp)
  u16*   rb1   = (u16*)(ws + 19922944);  // 2MB rank buf
  u16*   z16   = (u16*)(ws + 22020096);  // 1MB kv-latent
  u16*   rb2   = (u16*)(ws + 23068672);  // 2MB ku/vu ranks
  u16*   k16   = (u16*)(ws + 25165824);  // 2MB
  float* v32   = (float*)(ws + 27262976);// 4MB
  u16*   vt16  = (u16*)(ws + 31457280);  // 2MB
  u16*   q16   = (u16*)(ws + 33554432);  // 8MB
  u16*   ao16  = (u16*)(ws + 41943040);  // 8MB
  float* parts = (float*)(ws + 50331648);// <=32MB split-K / mlp partials
  u16*   t16   = (u16*)(ws + 83886080);  // 128KB value-emb rank
  float* x2    = (float*)d_out;

  ConvArgs ca;
  const int widx[15] = {4, 6, 5, 7, 8, 10, 9, 11, 12, 13, 18, 20, 21, 22, 23};
  for (int i = 0; i < 15; ++i) ca.s[i] = (const float*)d_in[widx[i]];
  for (int i = 0; i < 16; ++i) ca.off[i] = WOFF[i];

  // fused prep: weight convert + attn rmsnorm + value-emb rank GEMM
  prep_k<<<5096, 256, 0, stream>>>(ca, W16, x, anw, xa16, ids, vemb, vpB, t16);

  // fused hop1: xa @ [qB;kvB].T  (N=512, split-K 4)
  gemm_nt<64, 0><<<dim3(16, 4, 4), 256, 0, stream>>>(xa16, qkB16, parts, 2048, 512, 2048, 2048, nullptr, nullptr, nullptr, nullptr);
  redcvt_k<<<1024, 256, 0, stream>>>(parts, rb1, 262144, 4);
  // q = rope(rms(rb1[:, :256] @ qA.T)) * gain*scale  [validated R12]
  hop2q_k<<<dim3(16, 16), 256, 0, stream>>>(rb1, qA16, q16, q_gain);
  // z = rb1[:, 256:] @ kvA.T
  gemm_nt<64, 1><<<dim3(16, 2, 1), 256, 0, stream>>>(rb1 + 256, kvA16, z16, 2048, 256, 256, 512, nullptr, nullptr, nullptr, nullptr);
  // fused ku/vu hop1: z @ [kuB;vuB].T  (N=512)
  gemm_nt<64, 1><<<dim3(16, 4, 1), 256, 0, stream>>>(z16, kuvuB16, rb2, 2048, 512, 256, 256, nullptr, nullptr, nullptr, nullptr);
  // k = rms(rb2[:, :256] @ kuA.T) fused epilogue  [validated R9]
  hop2k_k<<<dim3(16, 4), 256, 0, stream>>>(rb2, kuA16, k16);
  // v = rb2[:, 256:] @ vuA.T + t16 @ vpA.T   (DUAL, f32 out)  [proven]
  gemm_nt<64, 0, true><<<dim3(16, 4, 1), 256, 0, stream>>>(rb2 + 256, vuA16, v32, 2048, 512, 256, 512, nullptr, nullptr, t16, vpA16);
  vtprep_k<<<dim3(32, 8), 256, 0, stream>>>(v32, vt16);
  // attention (single pass, direct bf16 out)
  attn_k<<<256, 256, 0, stream>>>(q16, k16, vt16, ao16, wptr);
  // o-proj: hop1 split-8, redcvt, hop2 fused with residual (x + sc*o)
  gemm_nt<64, 0><<<dim3(16, 2, 8), 256, 0, stream>>>(ao16, oB16, parts, 2048, 256, 2048, 2048, nullptr, nullptr, nullptr, nullptr);
  redcvt_k<<<512, 256, 0, stream>>>(parts, rb1, 131072, 8);
  gemm_nt<64, 4><<<dim3(16, 16, 1), 256, 0, stream>>>(rb1, oA16, x2, 2048, 2048, 256, 256, x, attn_scale, nullptr, nullptr);
  // mlp
  rmsnorm_k<<<2048, 256, 0, stream>>>(x2, mnw, xa16, 1e-6f);
  gemm_nt<64, 0><<<dim3(16, 1, 8), 256, 0, stream>>>(xa16, fcB16, parts, 2048, 128, 2048, 2048, nullptr, nullptr, nullptr, nullptr);
  redcvt_k<<<256, 256, 0, stream>>>(parts, rb1, 65536, 8);
  mlp_mid_k<<<dim3(16, 1, 32), 256, 0, stream>>>(rb1, fcA16, fc2B16, parts);
  redcvt_k<<<256, 256, 0, stream>>>(parts, rb1, 65536, 32);
  gemm_nt<64, 4><<<dim3(16, 16, 1), 256, 0, stream>>>(rb1, fc2A16, x2, 2048, 2048, 128, 128, x2, mlp_scale, nullptr, nullptr);
}

// Round 15
// 195.568 us; speedup vs baseline: 1.2109x; 1.0351x over previous
//
#include <hip/hip_runtime.h>
#include <cstdint>
#include <cstddef>

typedef unsigned short u16;
typedef __attribute__((ext_vector_type(4))) float f32x4;
typedef __attribute__((ext_vector_type(8))) short bf16x8;

#define SEQT 2048
#define DIMN 2048

__device__ __forceinline__ float bf2f(u16 h){
  union { unsigned int u; float f; } v; v.u = ((unsigned int)h) << 16; return v.f;
}
__device__ __forceinline__ u16 f2bf(float f){
  union { float f; unsigned int u; } v; v.f = f;
  unsigned int r = v.u + 0x7fffu + ((v.u >> 16) & 1u);
  return (u16)(r >> 16);
}
__device__ __forceinline__ float fexp2(float x){
  float r;
  asm("v_exp_f32 %0, %1" : "=v"(r) : "v"(x));
  return r;
}
__device__ __forceinline__ unsigned int cvtpk(float lo, float hi){
  unsigned int r;
  asm("v_cvt_pk_bf16_f32 %0, %1, %2" : "=v"(r) : "v"(lo), "v"(hi));
  return r;
}

typedef const __attribute__((address_space(1))) unsigned int* gas1_t;
typedef __attribute__((address_space(3))) unsigned int* las3_t;
__device__ __forceinline__ void gload_lds16(const void* g, void* l){
  __builtin_amdgcn_global_load_lds((gas1_t)g, (las3_t)l, 16, 0, 0);
}

// ---------------------------------------------------------------------------
// Generic NT GEMM: C[m,n] = sum_k A[m,k]*B[n,k], A:(M,lda) bf16, B:(N,K) bf16.
// BM=128, BN=128; 256 threads = 4 waves 2x2, each 64x64 (4x4 frags).
// EPI: 0 f32 store (+z-offset, split-K), 1 bf16 store, 4 f32 = Xres+SC[col]*acc
// DUAL: adds a K2=32 tail  acc += A2 @ B2^T  (reg-direct, no LDS).
// NOTE (R13 lesson): for K=2048 skinny-N, keep split-K >= 4 — the serial
// K-loop latency at low block counts costs far more than the redcvt pass.
// ---------------------------------------------------------------------------
template<int BK, int EPI, bool DUAL = false>
__global__ __launch_bounds__(256, 2) void gemm_nt(
    const u16* __restrict__ A, const u16* __restrict__ B, void* __restrict__ Cv,
    int M, int N, int K, int lda, const float* __restrict__ Xres,
    const float* __restrict__ SC, const u16* __restrict__ A2,
    const u16* __restrict__ B2)
{
  __shared__ u16 As[128 * BK];
  __shared__ u16 Bs[128 * BK];
  constexpr int ITER = (128 * BK) / 2048;
  constexpr int GM = BK / 8 - 1;
  const int t = threadIdx.x;
  const int w = t >> 6, l = t & 63;
  const int lr = l & 15, lg = l >> 4;
  const int brow = blockIdx.x << 7, bcol = blockIdx.y << 7;
  const int wr = (w >> 1) << 6, wc = (w & 1) << 6;
  const int Kc = K / gridDim.z;
  const int kbeg = blockIdx.z * Kc;
  const int kend = kbeg + Kc;
  f32x4 acc[4][4] = {};
  for (int k0 = kbeg; k0 < kend; k0 += BK) {
    __syncthreads();
#pragma unroll
    for (int i = 0; i < ITER; ++i) {
      int eo = i * 2048 + t * 8;
      int row = eo / BK;
      int cg = (eo & (BK - 1)) >> 3;
      int scol = ((cg ^ row) & GM) << 3;       // pre-swizzled global source
      gload_lds16(A + (size_t)(brow + row) * lda + k0 + scol, &As[eo]);
      gload_lds16(B + (size_t)(bcol + row) * K + k0 + scol, &Bs[eo]);
    }
    __syncthreads();
#pragma unroll
    for (int ks = 0; ks < BK / 32; ++ks) {
      bf16x8 aF[4], bF[4];
#pragma unroll
      for (int m = 0; m < 4; ++m) {
        int row = wr + m * 16 + lr;
        int kg = ks * 4 + lg;
        aF[m] = *(const bf16x8*)&As[row * BK + (((kg ^ row) & GM) << 3)];
      }
#pragma unroll
      for (int n = 0; n < 4; ++n) {
        int row = wc + n * 16 + lr;
        int kg = ks * 4 + lg;
        bF[n] = *(const bf16x8*)&Bs[row * BK + (((kg ^ row) & GM) << 3)];
      }
#pragma unroll
      for (int m = 0; m < 4; ++m)
#pragma unroll
        for (int n = 0; n < 4; ++n)
          acc[m][n] = __builtin_amdgcn_mfma_f32_16x16x32_bf16(aF[m], bF[n], acc[m][n], 0, 0, 0);
    }
  }
  if constexpr (DUAL) {
    bf16x8 aF2[4], bF2[4];
#pragma unroll
    for (int m = 0; m < 4; ++m)
      aF2[m] = *(const bf16x8*)(A2 + (size_t)(brow + wr + m * 16 + lr) * 32 + lg * 8);
#pragma unroll
    for (int n = 0; n < 4; ++n)
      bF2[n] = *(const bf16x8*)(B2 + (size_t)(bcol + wc + n * 16 + lr) * 32 + lg * 8);
#pragma unroll
    for (int m = 0; m < 4; ++m)
#pragma unroll
      for (int n = 0; n < 4; ++n)
        acc[m][n] = __builtin_amdgcn_mfma_f32_16x16x32_bf16(aF2[m], bF2[n], acc[m][n], 0, 0, 0);
  }
  const size_t zoff = (size_t)blockIdx.z * (size_t)M * (size_t)N;
#pragma unroll
  for (int m = 0; m < 4; ++m)
#pragma unroll
    for (int n = 0; n < 4; ++n)
#pragma unroll
      for (int j = 0; j < 4; ++j) {
        int row = brow + wr + m * 16 + lg * 4 + j;
        int col = bcol + wc + n * 16 + lr;
        float v = acc[m][n][j];
        if constexpr (EPI == 0) ((float*)Cv)[zoff + (size_t)row * N + col] = v;
        else if constexpr (EPI == 1) ((u16*)Cv)[(size_t)row * N + col] = f2bf(v);
        else {
          float xo = Xres[(size_t)row * N + col];
          ((float*)Cv)[(size_t)row * N + col] = xo + SC[col] * v;
        }
      }
}

// ---------------------------------------------------------------------------
// hop2k: k16 = rms_HEPS_per_head( rb2[:, :256] @ kuA^T ).  4x1 wave layout:
// each wave owns 32 rows x 128 cols (one kv-head per blockIdx.y) so the
// per-row sum-of-squares is ENTIRELY intra-wave.  [VALIDATED R9]
// ---------------------------------------------------------------------------
__global__ __launch_bounds__(256, 2) void hop2k_k(
    const u16* __restrict__ rb2, const u16* __restrict__ kuA,
    u16* __restrict__ k16)
{
  __shared__ u16 As[128 * 64];
  __shared__ u16 Bs[128 * 64];
  const int t = threadIdx.x, w = t >> 6, l = t & 63;
  const int lr = l & 15, lg = l >> 4;
  const int brow = blockIdx.x << 7;
  const int bcol = blockIdx.y << 7;            // one kv-head per y
  const u16* B = kuA + (size_t)bcol * 256;
  const int wr2 = w << 5;                      // wave: 32 rows x 128 cols
  f32x4 acc[2][8] = {};
  for (int k0 = 0; k0 < 256; k0 += 64) {
    __syncthreads();
#pragma unroll
    for (int i = 0; i < 4; ++i) {
      int eo = i * 2048 + t * 8;
      int row = eo >> 6, cg = (eo >> 3) & 7;
      int scol = ((cg ^ row) & 7) << 3;
      gload_lds16(rb2 + (size_t)(brow + row) * 512 + k0 + scol, &As[eo]);
      gload_lds16(B + (size_t)row * 256 + k0 + scol, &Bs[eo]);
    }
    __syncthreads();
#pragma unroll
    for (int ks = 0; ks < 2; ++ks) {
      bf16x8 aF[2], bF[8];
#pragma unroll
      for (int m = 0; m < 2; ++m) {
        int row = wr2 + m * 16 + lr, kg = ks * 4 + lg;
        aF[m] = *(const bf16x8*)&As[(row << 6) + (((kg ^ row) & 7) << 3)];
      }
#pragma unroll
      for (int n = 0; n < 8; ++n) {
        int row = n * 16 + lr, kg = ks * 4 + lg;
        bF[n] = *(const bf16x8*)&Bs[(row << 6) + (((kg ^ row) & 7) << 3)];
      }
#pragma unroll
      for (int m = 0; m < 2; ++m)
#pragma unroll
        for (int n = 0; n < 8; ++n)
          acc[m][n] = __builtin_amdgcn_mfma_f32_16x16x32_bf16(aF[m], bF[n], acc[m][n], 0, 0, 0);
    }
  }
#pragma unroll
  for (int m = 0; m < 2; ++m)
#pragma unroll
    for (int j = 0; j < 4; ++j) {
      float s = 0.f;
#pragma unroll
      for (int n = 0; n < 8; ++n) { float v = acc[m][n][j]; s += v * v; }
#pragma unroll
      for (int mm = 1; mm < 16; mm <<= 1) s += __shfl_xor(s, mm);
      float rs = rsqrtf(s * (1.0f / 128.0f) + 1.1920929e-07f);
      int row = brow + wr2 + m * 16 + lg * 4 + j;
#pragma unroll
      for (int n = 0; n < 8; ++n)
        k16[(size_t)row * 512 + bcol + n * 16 + lr] = f2bf(acc[m][n][j] * rs);
    }
}

// ---------------------------------------------------------------------------
// hop2qz [MERGED, this round]: one dispatch, grid (16, 18).
//   y < 16:  q16 = gain*scale*rope( rms_HEPS( rb1[:, :256] @ qA^T ) )  (head y)
//            -- byte-identical to hop2q [VALIDATED R12]
//   y >= 16: z16[:, (y-16)*128 ..] = bf16( rb1[:, 256:] @ kvA^T )
//            -- same 4x1 skeleton, plain store epilogue
// No ssred, no transposed write (the two implicated failure elements).
// ---------------------------------------------------------------------------
__global__ __launch_bounds__(256, 2) void hop2qz_k(
    const u16* __restrict__ rb1, const u16* __restrict__ qA,
    const u16* __restrict__ kvA, u16* __restrict__ q16,
    u16* __restrict__ z16, const float* __restrict__ gain)
{
  __shared__ u16 As[128 * 64];
  __shared__ u16 Bs[128 * 64];
  const int t = threadIdx.x, w = t >> 6, l = t & 63;
  const int lr = l & 15, lg = l >> 4;
  const int brow = blockIdx.x << 7;
  const bool qpath = blockIdx.y < 16;
  const int hh = blockIdx.y;                        // qpath head
  const int bcol = (blockIdx.y - 16) << 7;          // zpath col block
  const u16* A = qpath ? rb1 : rb1 + 256;
  const u16* B = qpath ? qA + ((size_t)hh << 7) * 256 : kvA + (size_t)bcol * 256;
  const int wr2 = w << 5;
  f32x4 acc[2][8] = {};
  for (int k0 = 0; k0 < 256; k0 += 64) {
    __syncthreads();
#pragma unroll
    for (int i = 0; i < 4; ++i) {
      int eo = i * 2048 + t * 8;
      int row = eo >> 6, cg = (eo >> 3) & 7;
      int scol = ((cg ^ row) & 7) << 3;
      gload_lds16(A + (size_t)(brow + row) * 512 + k0 + scol, &As[eo]);
      gload_lds16(B + (size_t)row * 256 + k0 + scol, &Bs[eo]);
    }
    __syncthreads();
#pragma unroll
    for (int ks = 0; ks < 2; ++ks) {
      bf16x8 aF[2], bF[8];
#pragma unroll
      for (int m = 0; m < 2; ++m) {
        int row = wr2 + m * 16 + lr, kg = ks * 4 + lg;
        aF[m] = *(const bf16x8*)&As[(row << 6) + (((kg ^ row) & 7) << 3)];
      }
#pragma unroll
      for (int n = 0; n < 8; ++n) {
        int row = n * 16 + lr, kg = ks * 4 + lg;
        bF[n] = *(const bf16x8*)&Bs[(row << 6) + (((kg ^ row) & 7) << 3)];
      }
#pragma unroll
      for (int m = 0; m < 2; ++m)
#pragma unroll
        for (int n = 0; n < 8; ++n)
          acc[m][n] = __builtin_amdgcn_mfma_f32_16x16x32_bf16(aF[m], bF[n], acc[m][n], 0, 0, 0);
    }
  }
  if (qpath) {
    const float gm = gain[hh] * 0.08838834764831845f * 1.4426950408889634f; // 1/sqrt(128)*log2e
#pragma unroll
    for (int m = 0; m < 2; ++m)
#pragma unroll
      for (int j = 0; j < 4; ++j) {
        float s = 0.f;
#pragma unroll
        for (int n = 0; n < 8; ++n) { float v = acc[m][n][j]; s += v * v; }
#pragma unroll
        for (int mm = 1; mm < 16; mm <<= 1) s += __shfl_xor(s, mm);
        float rs = rsqrtf(s * (1.0f / 128.0f) + 1.1920929e-07f) * gm;
        int row = brow + wr2 + m * 16 + lg * 4 + j;   // token position
#pragma unroll
        for (int n = 0; n < 2; ++n) {
          float fr = __expf(-(float)(n * 16 + lr) * 0.28782313662425574f); // ln(1e4)/32
          float f = (float)row * fr;
          float c = cosf(f), sn = sinf(f);
          float a1 = acc[m][n][j], a2 = acc[m][n + 2][j];
          acc[m][n][j] = a1 * c + a2 * sn;
          acc[m][n + 2][j] = a2 * c - a1 * sn;
        }
#pragma unroll
        for (int n = 0; n < 8; ++n)
          q16[(size_t)row * 2048 + (hh << 7) + n * 16 + lr] = f2bf(acc[m][n][j] * rs);
      }
  } else {
#pragma unroll
    for (int m = 0; m < 2; ++m)
#pragma unroll
      for (int j = 0; j < 4; ++j) {
        int row = brow + wr2 + m * 16 + lg * 4 + j;
#pragma unroll
        for (int n = 0; n < 8; ++n)
          z16[(size_t)row * 256 + bcol + n * 16 + lr] = f2bf(acc[m][n][j]);
      }
  }
}

// ---------------------------------------------------------------------------
// Fused MLP middle: parts[z] = relu^2(rb1 @ fcA^T)_chunk @ fc2B_chunk^T
// z=16 config (4 chunks/block) — halves partial traffic vs z=32 [R4-validated]
// ---------------------------------------------------------------------------
__global__ __launch_bounds__(256, 2) void mlp_mid_k(
    const u16* __restrict__ rb1, const u16* __restrict__ fcA,
    const u16* __restrict__ fc2B, float* __restrict__ parts)
{
  __shared__ u16 Hs[128 * 128];
  const int t = threadIdx.x, w = t >> 6, l = t & 63;
  const int lr = l & 15, lg = l >> 4;
  const int brow = blockIdx.x << 7;
  const int z = blockIdx.z;
  const int hidOff = (w >> 1) << 6, mOff = (w & 1) << 6;   // hop1 wave layout
  const int mOff2 = (w >> 1) << 6, r2Off = (w & 1) << 6;   // hop2 wave layout
  f32x4 acc2[4][4] = {};
#pragma unroll 1
  for (int cc = 0; cc < 4; ++cc) {
    const int H0 = (z * 4 + cc) << 7;
    bf16x8 rb1F[4][4];
#pragma unroll
    for (int mt = 0; mt < 4; ++mt)
#pragma unroll
      for (int ks = 0; ks < 4; ++ks)
        rb1F[mt][ks] = *(const bf16x8*)(rb1 + (size_t)(brow + mOff + mt * 16 + lr) * 128 + ks * 32 + lg * 8);
    f32x4 acc1[4][4] = {};   // [hn][mt]
#pragma unroll
    for (int hn = 0; hn < 4; ++hn) {
      bf16x8 aF[4];
#pragma unroll
      for (int ks = 0; ks < 4; ++ks)
        aF[ks] = *(const bf16x8*)(fcA + (size_t)(H0 + hidOff + hn * 16 + lr) * 128 + ks * 32 + lg * 8);
#pragma unroll
      for (int mt = 0; mt < 4; ++mt)
#pragma unroll
        for (int ks = 0; ks < 4; ++ks)
          acc1[hn][mt] = __builtin_amdgcn_mfma_f32_16x16x32_bf16(aF[ks], rb1F[mt][ks], acc1[hn][mt], 0, 0, 0);
    }
#pragma unroll
    for (int hn = 0; hn < 4; ++hn)
#pragma unroll
      for (int mt = 0; mt < 4; ++mt) {
        float r0 = acc1[hn][mt][0] > 0.f ? acc1[hn][mt][0] * acc1[hn][mt][0] : 0.f;
        float r1 = acc1[hn][mt][1] > 0.f ? acc1[hn][mt][1] * acc1[hn][mt][1] : 0.f;
        float r2 = acc1[hn][mt][2] > 0.f ? acc1[hn][mt][2] * acc1[hn][mt][2] : 0.f;
        float r3 = acc1[hn][mt][3] > 0.f ? acc1[hn][mt][3] * acc1[hn][mt][3] : 0.f;
        uint2 pk; pk.x = cvtpk(r0, r1); pk.y = cvtpk(r2, r3);
        int m = mOff + mt * 16 + lr;
        int hl = hidOff + hn * 16 + lg * 4;
        int cg = hl >> 3;
        *(uint2*)((char*)Hs + m * 256 + (((cg ^ (m & 7)) << 4) | ((hl & 7) << 1))) = pk;
      }
    __syncthreads();
#pragma unroll
    for (int ks2 = 0; ks2 < 4; ++ks2) {
      bf16x8 hF[4];
#pragma unroll
      for (int mt = 0; mt < 4; ++mt) {
        int m = mOff2 + mt * 16 + lr;
        int hl = ks2 * 32 + lg * 8;
        int cg = hl >> 3;
        hF[mt] = *(const bf16x8*)((const char*)Hs + m * 256 + (((cg ^ (m & 7)) << 4)));
      }
#pragma unroll
      for (int nf = 0; nf < 4; ++nf) {
        bf16x8 bF = *(const bf16x8*)(fc2B + (size_t)(r2Off + nf * 16 + lr) * 8192 + H0 + ks2 * 32 + lg * 8);
#pragma unroll
        for (int mt = 0; mt < 4; ++mt)
          acc2[mt][nf] = __builtin_amdgcn_mfma_f32_16x16x32_bf16(hF[mt], bF, acc2[mt][nf], 0, 0, 0);
      }
    }
    __syncthreads();
  }
  float* P = parts + (size_t)z * 2048 * 128;
#pragma unroll
  for (int mt = 0; mt < 4; ++mt)
#pragma unroll
    for (int nf = 0; nf < 4; ++nf)
#pragma unroll
      for (int j = 0; j < 4; ++j)
        P[(size_t)(brow + mOff2 + mt * 16 + lg * 4 + j) * 128 + r2Off + nf * 16 + lr] = acc2[mt][nf][j];
}

// Sum split-K partials -> bf16 (vectorized: n4 = n/4)
__global__ __launch_bounds__(256) void redcvt_k(const float* __restrict__ parts,
                                                u16* __restrict__ out, int n4, int S)
{
  int i = blockIdx.x * 256 + threadIdx.x;
  if (i >= n4) return;
  float4 s = make_float4(0.f, 0.f, 0.f, 0.f);
  for (int z = 0; z < S; ++z) {
    float4 v = ((const float4*)parts)[(size_t)z * n4 + i];
    s.x += v.x; s.y += v.y; s.z += v.z; s.w += v.w;
  }
  uint2 o; o.x = cvtpk(s.x, s.y); o.y = cvtpk(s.z, s.w);
  ((uint2*)out)[i] = o;
}

// ---------------------------------------------------------------------------
// Fused prep: weight f32->bf16 conversion + attn rmsnorm + value-emb rank GEMM
// ---------------------------------------------------------------------------
struct ConvArgs { const float* s[15]; int off[16]; };

__device__ __forceinline__ void rms_body(const float* __restrict__ xr,
                                         const float* __restrict__ wg,
                                         u16* __restrict__ orow, float eps,
                                         __shared__ float* red)
{
  float v[8]; float ss = 0.f;
#pragma unroll
  for (int i = 0; i < 8; ++i) { v[i] = xr[threadIdx.x + i * 256]; ss += v[i] * v[i]; }
#pragma unroll
  for (int m = 1; m < 64; m <<= 1) ss += __shfl_xor(ss, m);
  if ((threadIdx.x & 63) == 0) red[threadIdx.x >> 6] = ss;
  __syncthreads();
  float tot = red[0] + red[1] + red[2] + red[3];
  float rs = rsqrtf(tot * (1.0f / DIMN) + eps);
#pragma unroll
  for (int i = 0; i < 8; ++i) { int c = threadIdx.x + i * 256; orow[c] = f2bf(v[i] * rs * wg[c]); }
}

__global__ __launch_bounds__(256) void prep_k(ConvArgs a, u16* __restrict__ dst,
                                              const float* __restrict__ x,
                                              const float* __restrict__ anw,
                                              u16* __restrict__ xa,
                                              const int* __restrict__ ids,
                                              const float* __restrict__ emb,
                                              const float* __restrict__ vpB,
                                              u16* __restrict__ t16)
{
  __shared__ float red[4];
  const int b = blockIdx.x;
  if (b < 2792) {
    int i = b * 256 + threadIdx.x;
    if (i >= 714752) return;
    int i8 = i * 8;
    int seg = 0;
#pragma unroll
    for (int k = 1; k < 15; ++k) if (i8 >= a.off[k]) seg = k;
    const float* s = a.s[seg] + (i8 - a.off[seg]);
    float4 f0 = *(const float4*)s, f1 = *(const float4*)(s + 4);
    uint4 o; o.x = cvtpk(f0.x, f0.y); o.y = cvtpk(f0.z, f0.w);
    o.z = cvtpk(f1.x, f1.y); o.w = cvtpk(f1.z, f1.w);
    *(uint4*)(dst + i8) = o;
  } else if (b < 2792 + 2048) {
    int row = b - 2792;
    rms_body(x + (size_t)row * DIMN, anw, xa + (size_t)row * DIMN, 1e-6f, red);
  } else {
    int idx = (b - 4840) * 256 + threadIdx.x;   // 2048*32
    int m = idx >> 5, n = idx & 31;
    int id = ids[m]; id = id < 0 ? 0 : (id > 50256 ? 50256 : id);
    const float* e = emb + (size_t)id * 64;
    const float* wr = vpB + n * 64;
    float s = 0.f;
#pragma unroll
    for (int k = 0; k < 64; ++k) s += e[k] * wr[k];
    t16[idx] = f2bf(s);
  }
}

// rmsnorm (standalone, mlp)
__global__ __launch_bounds__(256) void rmsnorm_k(const float* __restrict__ x,
                                                 const float* __restrict__ wg,
                                                 u16* __restrict__ o, float eps)
{
  __shared__ float red[4];
  int row = blockIdx.x;
  rms_body(x + (size_t)row * DIMN, wg, o + (size_t)row * DIMN, eps, red);
}

// vt[d][t] = bf16(v32[t][d]) via 64x64 LDS tile transpose  [proven]
__global__ __launch_bounds__(256) void vtprep_k(const float* __restrict__ v32, u16* __restrict__ vt)
{
  __shared__ float tile[64][65];
  const int t0 = blockIdx.x << 6;
  const int d0 = blockIdx.y << 6;
  int tr = threadIdx.x >> 4;
  int c4 = threadIdx.x & 15;
#pragma unroll
  for (int i = 0; i < 4; ++i) {
    int row = tr + i * 16;
    float4 v = *(const float4*)(v32 + (size_t)(t0 + row) * 512 + d0 + c4 * 4);
    tile[row][c4 * 4 + 0] = v.x; tile[row][c4 * 4 + 1] = v.y;
    tile[row][c4 * 4 + 2] = v.z; tile[row][c4 * 4 + 3] = v.w;
  }
  __syncthreads();
  int dl = threadIdx.x >> 2;
  int ts = (threadIdx.x & 3) * 16;
  u16* orow = vt + (size_t)(d0 + dl) * 2048 + t0 + ts;
#pragma unroll
  for (int k = 0; k < 16; k += 2) {
    unsigned int pk = cvtpk(tile[ts + k][dl], tile[ts + k + 1][dl]);
    *(unsigned int*)(orow + k) = pk;
  }
}

// ---------------------------------------------------------------------------
// Flash attention: kv-head-shared, no split, double-buffered counted-vmcnt.
// Grid 256 blocks = (kh, 32 q-rows); 4 waves = 4 heads of kh share K/V tiles.
// ---------------------------------------------------------------------------
__device__ __forceinline__ int read_window(const int* wptr){
  int W = *wptr;
  if (W > 65536 || W < 0) { union { int i; float f; } u; u.i = W; W = (int)u.f; }
  if (W < 1) W = 1;
  if (W > SEQT) W = SEQT;
  return W;
}

__global__ __launch_bounds__(256, 2) void attn_k(
    const u16* __restrict__ Q, const u16* __restrict__ Kx, const u16* __restrict__ Vt,
    u16* __restrict__ O, const int* __restrict__ wptr)
{
  __shared__ u16 Ks[2][64 * 128];
  __shared__ u16 Vs[2][128 * 64];
  __shared__ u16 Pl[4][2][16 * 64];
  const int t = threadIdx.x;
  const int w = t >> 6, l = t & 63;
  const int lr = l & 15, lg = l >> 4;
  const int kh = blockIdx.x >> 6, qb = blockIdx.x & 63;  // flat%8 = qb%8 -> XCD spread
  const int h = kh * 4 + w;                              // wave = head
  const int qb0 = qb << 5;
  const int W = read_window(wptr);
  int kstart = qb0 - W + 1;
  if (kstart < 0) kstart = 0;
  kstart &= ~63;
  const int kc_max = (qb0 + 31) & ~63;
  const int nt = ((kc_max - kstart) >> 6) + 1;
  bf16x8 qF[2][4];
#pragma unroll
  for (int g = 0; g < 2; ++g)
#pragma unroll
    for (int ks = 0; ks < 4; ++ks)
      qF[g][ks] = *(const bf16x8*)(Q + (size_t)(qb0 + g * 16 + lr) * DIMN + h * 128 + ks * 32 + lg * 8);
  f32x4 oacc[2][8] = {};
  float lsum[2] = {0.f, 0.f};
  const int swz = (lr & 7) << 4;
  char* PlB0 = (char*)&Pl[w][0][0] + lr * 128;
  char* PlB1 = (char*)&Pl[w][1][0] + lr * 128;

  auto stage = [&](int buf, int kc){
#pragma unroll
    for (int i = 0; i < 4; ++i) {
      int eo = i * 2048 + t * 8;
      int row = eo >> 7, cg = (eo >> 3) & 15;
      gload_lds16(Kx + (size_t)(kc + row) * 512 + kh * 128 + (((cg ^ row) & 15) << 3), &Ks[buf][eo]);
    }
#pragma unroll
    for (int i = 0; i < 4; ++i) {
      int eo = i * 2048 + t * 8;
      int d = eo >> 6, kg = (eo >> 3) & 7;
      gload_lds16(Vt + (size_t)kh * (128 * SEQT) + (size_t)d * SEQT + kc + (((kg ^ d) & 7) << 3), &Vs[buf][eo]);
    }
  };

  stage(0, kstart);
  for (int tt = 0; tt < nt; ++tt) {
    const int kc = kstart + (tt << 6);
    const int nx = (tt + 1 < nt) ? tt + 1 : tt;   // dummy re-stage on last iter
    stage((tt + 1) & 1, kstart + (nx << 6));
    asm volatile("s_waitcnt vmcnt(8)" ::: "memory");   // tile tt landed; tt+1 in flight
    __builtin_amdgcn_sched_barrier(0);
    __builtin_amdgcn_s_barrier();
    const u16* KsC = &Ks[tt & 1][0];
    const u16* VsC = &Vs[tt & 1][0];
    f32x4 sf0[4] = {}, sf1[4] = {};
#pragma unroll
    for (int ks = 0; ks < 4; ++ks)
#pragma unroll
      for (int n = 0; n < 4; ++n) {
        int row = n * 16 + lr, kg = ks * 4 + lg;
        bf16x8 kF = *(const bf16x8*)&KsC[(row << 7) + (((kg ^ row) & 15) << 3)];
        sf0[n] = __builtin_amdgcn_mfma_f32_16x16x32_bf16(kF, qF[0][ks], sf0[n], 0, 0, 0);
        sf1[n] = __builtin_amdgcn_mfma_f32_16x16x32_bf16(kF, qF[1][ks], sf1[n], 0, 0, 0);
      }
#pragma unroll
    for (int g = 0; g < 2; ++g) {
      f32x4* sf = g ? sf1 : sf0;
      char* PlB = g ? PlB1 : PlB0;
      const int qg0 = qb0 + g * 16;
      const int qi = qg0 + lr;
      const bool fullv = ((kc + 63) <= qg0) && ((qg0 + 15 - kc) < W);
      if (fullv) {
#pragma unroll
        for (int n = 0; n < 4; ++n)
#pragma unroll
          for (int j = 0; j < 4; ++j) {
            float p = fexp2(sf[n][j]);
            sf[n][j] = p; lsum[g] += p;
          }
      } else {
#pragma unroll
        for (int n = 0; n < 4; ++n)
#pragma unroll
          for (int j = 0; j < 4; ++j) {
            int kj = kc + n * 16 + lg * 4 + j;
            bool vld = (kj <= qi) && ((qi - kj) < W);
            float p = vld ? fexp2(sf[n][j]) : 0.f;
            sf[n][j] = p; lsum[g] += p;
          }
      }
#pragma unroll
      for (int n = 0; n < 4; ++n) {
        uint2 pk;
        pk.x = cvtpk(sf[n][0], sf[n][1]);
        pk.y = cvtpk(sf[n][2], sf[n][3]);
        *(uint2*)(PlB + ((n * 32 + lg * 8) ^ swz)) = pk;
      }
    }
#pragma unroll
    for (int ks = 0; ks < 2; ++ks) {
      int kgp = ks * 4 + lg;
      bf16x8 pF0 = *(const bf16x8*)(PlB0 + ((kgp * 16) ^ swz));
      bf16x8 pF1 = *(const bf16x8*)(PlB1 + ((kgp * 16) ^ swz));
#pragma unroll
      for (int nd = 0; nd < 8; ++nd) {
        int d = nd * 16 + lr;
        bf16x8 vF = *(const bf16x8*)&VsC[(d << 6) + (((kgp ^ d) & 7) << 3)];
        oacc[0][nd] = __builtin_amdgcn_mfma_f32_16x16x32_bf16(pF0, vF, oacc[0][nd], 0, 0, 0);
        oacc[1][nd] = __builtin_amdgcn_mfma_f32_16x16x32_bf16(pF1, vF, oacc[1][nd], 0, 0, 0);
      }
    }
    __builtin_amdgcn_s_barrier();   // all waves done reading buf before re-stage
  }
#pragma unroll
  for (int g = 0; g < 2; ++g) {
    float ls = lsum[g];
    ls += __shfl_xor(ls, 16);
    ls += __shfl_xor(ls, 32);
    float inv[4];
#pragma unroll
    for (int j = 0; j < 4; ++j) inv[j] = 1.0f / __shfl(ls, lg * 4 + j);
#pragma unroll
    for (int nd = 0; nd < 8; ++nd)
#pragma unroll
      for (int j = 0; j < 4; ++j)
        O[(size_t)(qb0 + g * 16 + lg * 4 + j) * DIMN + h * 128 + nd * 16 + lr] =
            f2bf(oacc[g][nd][j] * inv[j]);
  }
}

// ---------------------------------------------------------------------------
extern "C" void kernel_launch(void* const* d_in, const int* in_sizes, int n_in,
                              void* d_out, int out_size, void* d_ws, size_t ws_size,
                              hipStream_t stream)
{
  (void)in_sizes; (void)n_in; (void)out_size; (void)ws_size;
  const float* x          = (const float*)d_in[0];
  const int*   ids        = (const int*)d_in[1];
  const int*   wptr       = (const int*)d_in[2];
  const float* anw        = (const float*)d_in[3];
  const float* attn_scale = (const float*)d_in[14];
  const float* q_gain     = (const float*)d_in[15];
  const float* vemb       = (const float*)d_in[16];
  const float* vpB        = (const float*)d_in[17];
  const float* mnw        = (const float*)d_in[19];
  const float* mlp_scale  = (const float*)d_in[24];

  char* ws = (char*)d_ws;
  u16* W16 = (u16*)ws;
  static const int WOFF[16] = {0, 524288, 1048576, 1572864, 1638400, 1703936,
                               1769472, 1900544, 2031616, 2555904, 3080192,
                               3096576, 3358720, 4407296, 5455872, 5718016};
  const u16* qkB16   = W16 + WOFF[0];   // 512 x 2048
  const u16* qA16    = W16 + WOFF[2];
  const u16* kvA16   = W16 + WOFF[3];
  const u16* kuvuB16 = W16 + WOFF[4];   // 512 x 256
  const u16* kuA16   = W16 + WOFF[6];
  const u16* vuA16   = W16 + WOFF[7];
  const u16* oB16    = W16 + WOFF[8];
  const u16* oA16    = W16 + WOFF[9];
  const u16* vpA16   = W16 + WOFF[10];
  const u16* fcB16   = W16 + WOFF[11];
  const u16* fcA16   = W16 + WOFF[12];
  const u16* fc2B16  = W16 + WOFF[13];
  const u16* fc2A16  = W16 + WOFF[14];

  u16*   xa16  = (u16*)(ws + 11534336);  // 8MB (norm output, q/kv then mlp)
  u16*   rb1   = (u16*)(ws + 19922944);  // 2MB rank buf
  u16*   z16   = (u16*)(ws + 22020096);  // 1MB kv-latent
  u16*   rb2   = (u16*)(ws + 23068672);  // 2MB ku/vu ranks
  u16*   k16   = (u16*)(ws + 25165824);  // 2MB
  float* v32   = (float*)(ws + 27262976);// 4MB
  u16*   vt16  = (u16*)(ws + 31457280);  // 2MB
  u16*   q16   = (u16*)(ws + 33554432);  // 8MB
  u16*   ao16  = (u16*)(ws + 41943040);  // 8MB
  float* parts = (float*)(ws + 50331648);// <=16MB split-K / mlp partials
  u16*   t16   = (u16*)(ws + 83886080);  // 128KB value-emb rank
  float* x2    = (float*)d_out;

  ConvArgs ca;
  const int widx[15] = {4, 6, 5, 7, 8, 10, 9, 11, 12, 13, 18, 20, 21, 22, 23};
  for (int i = 0; i < 15; ++i) ca.s[i] = (const float*)d_in[widx[i]];
  for (int i = 0; i < 16; ++i) ca.off[i] = WOFF[i];

  // fused prep: weight convert + attn rmsnorm + value-emb rank GEMM
  prep_k<<<5096, 256, 0, stream>>>(ca, W16, x, anw, xa16, ids, vemb, vpB, t16);

  // fused hop1: xa @ [qB;kvB].T  (N=512, split-K 4)
  gemm_nt<64, 0><<<dim3(16, 4, 4), 256, 0, stream>>>(xa16, qkB16, parts, 2048, 512, 2048, 2048, nullptr, nullptr, nullptr, nullptr);
  redcvt_k<<<1024, 256, 0, stream>>>(parts, rb1, 262144, 4);
  // merged q (rms+rope+gain epi) + z, one dispatch
  hop2qz_k<<<dim3(16, 18), 256, 0, stream>>>(rb1, qA16, kvA16, q16, z16, q_gain);
  // fused ku/vu hop1: z @ [kuB;vuB].T  (N=512)
  gemm_nt<64, 1><<<dim3(16, 4, 1), 256, 0, stream>>>(z16, kuvuB16, rb2, 2048, 512, 256, 256, nullptr, nullptr, nullptr, nullptr);
  // k = rms(rb2[:, :256] @ kuA.T) fused epilogue  [validated R9]
  hop2k_k<<<dim3(16, 4), 256, 0, stream>>>(rb2, kuA16, k16);
  // v = rb2[:, 256:] @ vuA.T + t16 @ vpA.T   (DUAL, f32 out)  [proven]
  gemm_nt<64, 0, true><<<dim3(16, 4, 1), 256, 0, stream>>>(rb2 + 256, vuA16, v32, 2048, 512, 256, 512, nullptr, nullptr, t16, vpA16);
  vtprep_k<<<dim3(32, 8), 256, 0, stream>>>(v32, vt16);
  // attention (single pass, direct bf16 out)
  attn_k<<<256, 256, 0, stream>>>(q16, k16, vt16, ao16, wptr);
  // o-proj: hop1 split-8, redcvt, hop2 fused with residual (x + sc*o)
  gemm_nt<64, 0><<<dim3(16, 2, 8), 256, 0, stream>>>(ao16, oB16, parts, 2048, 256, 2048, 2048, nullptr, nullptr, nullptr, nullptr);
  redcvt_k<<<512, 256, 0, stream>>>(parts, rb1, 131072, 8);
  gemm_nt<64, 4><<<dim3(16, 16, 1), 256, 0, stream>>>(rb1, oA16, x2, 2048, 2048, 256, 256, x, attn_scale, nullptr, nullptr);
  // mlp
  rmsnorm_k<<<2048, 256, 0, stream>>>(x2, mnw, xa16, 1e-6f);
  gemm_nt<64, 0><<<dim3(16, 1, 8), 256, 0, stream>>>(xa16, fcB16, parts, 2048, 128, 2048, 2048, nullptr, nullptr, nullptr, nullptr);
  redcvt_k<<<256, 256, 0, stream>>>(parts, rb1, 65536, 8);
  mlp_mid_k<<<dim3(16, 1, 16), 256, 0, stream>>>(rb1, fcA16, fc2B16, parts);
  redcvt_k<<<256, 256, 0, stream>>>(parts, rb1, 65536, 16);
  gemm_nt<64, 4><<<dim3(16, 16, 1), 256, 0, stream>>>(rb1, fc2A16, x2, 2048, 2048, 128, 128, x2, mlp_scale, nullptr, nullptr);
}

// Round 16
// 188.674 us; speedup vs baseline: 1.2552x; 1.0365x over previous
//
#include <hip/hip_runtime.h>
#include <cstdint>
#include <cstddef>

typedef unsigned short u16;
typedef __attribute__((ext_vector_type(4))) float f32x4;
typedef __attribute__((ext_vector_type(8))) short bf16x8;

#define SEQT 2048
#define DIMN 2048

__device__ __forceinline__ float bf2f(u16 h){
  union { unsigned int u; float f; } v; v.u = ((unsigned int)h) << 16; return v.f;
}
__device__ __forceinline__ u16 f2bf(float f){
  union { float f; unsigned int u; } v; v.f = f;
  unsigned int r = v.u + 0x7fffu + ((v.u >> 16) & 1u);
  return (u16)(r >> 16);
}
__device__ __forceinline__ float fexp2(float x){
  float r;
  asm("v_exp_f32 %0, %1" : "=v"(r) : "v"(x));
  return r;
}
__device__ __forceinline__ unsigned int cvtpk(float lo, float hi){
  unsigned int r;
  asm("v_cvt_pk_bf16_f32 %0, %1, %2" : "=v"(r) : "v"(lo), "v"(hi));
  return r;
}

typedef const __attribute__((address_space(1))) unsigned int* gas1_t;
typedef __attribute__((address_space(3))) unsigned int* las3_t;
__device__ __forceinline__ void gload_lds16(const void* g, void* l){
  __builtin_amdgcn_global_load_lds((gas1_t)g, (las3_t)l, 16, 0, 0);
}

// ---------------------------------------------------------------------------
// Generic NT GEMM: C[m,n] = sum_k A[m,k]*B[n,k], A:(M,lda) bf16, B:(N,K) bf16.
// BM=128, BN=128; 256 threads = 4 waves 2x2, each 64x64 (4x4 frags).
// EPI: 0 f32 store (+z-offset, split-K), 1 bf16 store, 4 f32 = Xres+SC[col]*acc
// NOTE (R13 lesson): for K=2048 skinny-N, keep split-K >= 4 — the serial
// K-loop latency at low block counts costs far more than the redcvt pass.
// ---------------------------------------------------------------------------
template<int BK, int EPI>
__global__ __launch_bounds__(256, 2) void gemm_nt(
    const u16* __restrict__ A, const u16* __restrict__ B, void* __restrict__ Cv,
    int M, int N, int K, int lda, const float* __restrict__ Xres,
    const float* __restrict__ SC)
{
  __shared__ u16 As[128 * BK];
  __shared__ u16 Bs[128 * BK];
  constexpr int ITER = (128 * BK) / 2048;
  constexpr int GM = BK / 8 - 1;
  const int t = threadIdx.x;
  const int w = t >> 6, l = t & 63;
  const int lr = l & 15, lg = l >> 4;
  const int brow = blockIdx.x << 7, bcol = blockIdx.y << 7;
  const int wr = (w >> 1) << 6, wc = (w & 1) << 6;
  const int Kc = K / gridDim.z;
  const int kbeg = blockIdx.z * Kc;
  const int kend = kbeg + Kc;
  f32x4 acc[4][4] = {};
  for (int k0 = kbeg; k0 < kend; k0 += BK) {
    __syncthreads();
#pragma unroll
    for (int i = 0; i < ITER; ++i) {
      int eo = i * 2048 + t * 8;
      int row = eo / BK;
      int cg = (eo & (BK - 1)) >> 3;
      int scol = ((cg ^ row) & GM) << 3;       // pre-swizzled global source
      gload_lds16(A + (size_t)(brow + row) * lda + k0 + scol, &As[eo]);
      gload_lds16(B + (size_t)(bcol + row) * K + k0 + scol, &Bs[eo]);
    }
    __syncthreads();
#pragma unroll
    for (int ks = 0; ks < BK / 32; ++ks) {
      bf16x8 aF[4], bF[4];
#pragma unroll
      for (int m = 0; m < 4; ++m) {
        int row = wr + m * 16 + lr;
        int kg = ks * 4 + lg;
        aF[m] = *(const bf16x8*)&As[row * BK + (((kg ^ row) & GM) << 3)];
      }
#pragma unroll
      for (int n = 0; n < 4; ++n) {
        int row = wc + n * 16 + lr;
        int kg = ks * 4 + lg;
        bF[n] = *(const bf16x8*)&Bs[row * BK + (((kg ^ row) & GM) << 3)];
      }
#pragma unroll
      for (int m = 0; m < 4; ++m)
#pragma unroll
        for (int n = 0; n < 4; ++n)
          acc[m][n] = __builtin_amdgcn_mfma_f32_16x16x32_bf16(aF[m], bF[n], acc[m][n], 0, 0, 0);
    }
  }
  const size_t zoff = (size_t)blockIdx.z * (size_t)M * (size_t)N;
#pragma unroll
  for (int m = 0; m < 4; ++m)
#pragma unroll
    for (int n = 0; n < 4; ++n)
#pragma unroll
      for (int j = 0; j < 4; ++j) {
        int row = brow + wr + m * 16 + lg * 4 + j;
        int col = bcol + wc + n * 16 + lr;
        float v = acc[m][n][j];
        if constexpr (EPI == 0) ((float*)Cv)[zoff + (size_t)row * N + col] = v;
        else if constexpr (EPI == 1) ((u16*)Cv)[(size_t)row * N + col] = f2bf(v);
        else {
          float xo = Xres[(size_t)row * N + col];
          ((float*)Cv)[(size_t)row * N + col] = xo + SC[col] * v;
        }
      }
}

// ---------------------------------------------------------------------------
// hop2kv [MERGED this round]: one dispatch, grid (16, 8).
//   y < 4:  k16 = rms_HEPS_per_head( rb2[:, :256] @ kuA^T )   (kv-head y)
//           -- byte-identical to hop2k [VALIDATED R9]
//   y >= 4: v32[:, (y-4)*128 ..] = f32( rb2[:,256:] @ vuA^T + t16 @ vpA^T )
//           -- same 4x1 skeleton + DUAL K2=32 tail, PLAIN row-major f32 store
// No ssred, no transposed write (the two implicated failure elements).
// ---------------------------------------------------------------------------
__global__ __launch_bounds__(256, 2) void hop2kv_k(
    const u16* __restrict__ rb2, const u16* __restrict__ kuA,
    const u16* __restrict__ vuA, u16* __restrict__ k16,
    float* __restrict__ v32, const u16* __restrict__ t16,
    const u16* __restrict__ vpA)
{
  __shared__ u16 As[128 * 64];
  __shared__ u16 Bs[128 * 64];
  const int t = threadIdx.x, w = t >> 6, l = t & 63;
  const int lr = l & 15, lg = l >> 4;
  const int brow = blockIdx.x << 7;
  const bool kpath = blockIdx.y < 4;
  const int bcol = (kpath ? blockIdx.y : (blockIdx.y - 4)) << 7;
  const u16* A = kpath ? rb2 : rb2 + 256;
  const u16* B = (kpath ? kuA : vuA) + (size_t)bcol * 256;
  const int wr2 = w << 5;                      // wave: 32 rows x 128 cols
  f32x4 acc[2][8] = {};
  for (int k0 = 0; k0 < 256; k0 += 64) {
    __syncthreads();
#pragma unroll
    for (int i = 0; i < 4; ++i) {
      int eo = i * 2048 + t * 8;
      int row = eo >> 6, cg = (eo >> 3) & 7;
      int scol = ((cg ^ row) & 7) << 3;
      gload_lds16(A + (size_t)(brow + row) * 512 + k0 + scol, &As[eo]);
      gload_lds16(B + (size_t)row * 256 + k0 + scol, &Bs[eo]);
    }
    __syncthreads();
#pragma unroll
    for (int ks = 0; ks < 2; ++ks) {
      bf16x8 aF[2], bF[8];
#pragma unroll
      for (int m = 0; m < 2; ++m) {
        int row = wr2 + m * 16 + lr, kg = ks * 4 + lg;
        aF[m] = *(const bf16x8*)&As[(row << 6) + (((kg ^ row) & 7) << 3)];
      }
#pragma unroll
      for (int n = 0; n < 8; ++n) {
        int row = n * 16 + lr, kg = ks * 4 + lg;
        bF[n] = *(const bf16x8*)&Bs[(row << 6) + (((kg ^ row) & 7) << 3)];
      }
#pragma unroll
      for (int m = 0; m < 2; ++m)
#pragma unroll
        for (int n = 0; n < 8; ++n)
          acc[m][n] = __builtin_amdgcn_mfma_f32_16x16x32_bf16(aF[m], bF[n], acc[m][n], 0, 0, 0);
    }
  }
  if (!kpath) {
    // rank-32 value-emb tail (reg-direct), fragment formulas mirror the
    // proven 2x2 DUAL path, re-indexed for 4x1 (m<2 rows, n<8 cols).
    bf16x8 aF2[2], bF2[8];
#pragma unroll
    for (int m = 0; m < 2; ++m)
      aF2[m] = *(const bf16x8*)(t16 + (size_t)(brow + wr2 + m * 16 + lr) * 32 + lg * 8);
#pragma unroll
    for (int n = 0; n < 8; ++n)
      bF2[n] = *(const bf16x8*)(vpA + (size_t)(bcol + n * 16 + lr) * 32 + lg * 8);
#pragma unroll
    for (int m = 0; m < 2; ++m)
#pragma unroll
      for (int n = 0; n < 8; ++n)
        acc[m][n] = __builtin_amdgcn_mfma_f32_16x16x32_bf16(aF2[m], bF2[n], acc[m][n], 0, 0, 0);
    // plain row-major f32 store (same form as gemm EPI=0)
#pragma unroll
    for (int m = 0; m < 2; ++m)
#pragma unroll
      for (int j = 0; j < 4; ++j) {
        int row = brow + wr2 + m * 16 + lg * 4 + j;
#pragma unroll
        for (int n = 0; n < 8; ++n)
          v32[(size_t)row * 512 + bcol + n * 16 + lr] = acc[m][n][j];
      }
    return;
  }
  // k path: per-row rms, fully intra-wave  [VALIDATED R9]
#pragma unroll
  for (int m = 0; m < 2; ++m)
#pragma unroll
    for (int j = 0; j < 4; ++j) {
      float s = 0.f;
#pragma unroll
      for (int n = 0; n < 8; ++n) { float v = acc[m][n][j]; s += v * v; }
#pragma unroll
      for (int mm = 1; mm < 16; mm <<= 1) s += __shfl_xor(s, mm);
      float rs = rsqrtf(s * (1.0f / 128.0f) + 1.1920929e-07f);
      int row = brow + wr2 + m * 16 + lg * 4 + j;
#pragma unroll
      for (int n = 0; n < 8; ++n)
        k16[(size_t)row * 512 + bcol + n * 16 + lr] = f2bf(acc[m][n][j] * rs);
    }
}

// ---------------------------------------------------------------------------
// hop2qz [VALIDATED R15]: one dispatch, grid (16, 18).
//   y < 16:  q16 = gain*scale*rope( rms_HEPS( rb1[:, :256] @ qA^T ) )  (head y)
//   y >= 16: z16[:, (y-16)*128 ..] = bf16( rb1[:, 256:] @ kvA^T )
// ---------------------------------------------------------------------------
__global__ __launch_bounds__(256, 2) void hop2qz_k(
    const u16* __restrict__ rb1, const u16* __restrict__ qA,
    const u16* __restrict__ kvA, u16* __restrict__ q16,
    u16* __restrict__ z16, const float* __restrict__ gain)
{
  __shared__ u16 As[128 * 64];
  __shared__ u16 Bs[128 * 64];
  const int t = threadIdx.x, w = t >> 6, l = t & 63;
  const int lr = l & 15, lg = l >> 4;
  const int brow = blockIdx.x << 7;
  const bool qpath = blockIdx.y < 16;
  const int hh = blockIdx.y;                        // qpath head
  const int bcol = (blockIdx.y - 16) << 7;          // zpath col block
  const u16* A = qpath ? rb1 : rb1 + 256;
  const u16* B = qpath ? qA + ((size_t)hh << 7) * 256 : kvA + (size_t)bcol * 256;
  const int wr2 = w << 5;
  f32x4 acc[2][8] = {};
  for (int k0 = 0; k0 < 256; k0 += 64) {
    __syncthreads();
#pragma unroll
    for (int i = 0; i < 4; ++i) {
      int eo = i * 2048 + t * 8;
      int row = eo >> 6, cg = (eo >> 3) & 7;
      int scol = ((cg ^ row) & 7) << 3;
      gload_lds16(A + (size_t)(brow + row) * 512 + k0 + scol, &As[eo]);
      gload_lds16(B + (size_t)row * 256 + k0 + scol, &Bs[eo]);
    }
    __syncthreads();
#pragma unroll
    for (int ks = 0; ks < 2; ++ks) {
      bf16x8 aF[2], bF[8];
#pragma unroll
      for (int m = 0; m < 2; ++m) {
        int row = wr2 + m * 16 + lr, kg = ks * 4 + lg;
        aF[m] = *(const bf16x8*)&As[(row << 6) + (((kg ^ row) & 7) << 3)];
      }
#pragma unroll
      for (int n = 0; n < 8; ++n) {
        int row = n * 16 + lr, kg = ks * 4 + lg;
        bF[n] = *(const bf16x8*)&Bs[(row << 6) + (((kg ^ row) & 7) << 3)];
      }
#pragma unroll
      for (int m = 0; m < 2; ++m)
#pragma unroll
        for (int n = 0; n < 8; ++n)
          acc[m][n] = __builtin_amdgcn_mfma_f32_16x16x32_bf16(aF[m], bF[n], acc[m][n], 0, 0, 0);
    }
  }
  if (qpath) {
    const float gm = gain[hh] * 0.08838834764831845f * 1.4426950408889634f; // 1/sqrt(128)*log2e
#pragma unroll
    for (int m = 0; m < 2; ++m)
#pragma unroll
      for (int j = 0; j < 4; ++j) {
        float s = 0.f;
#pragma unroll
        for (int n = 0; n < 8; ++n) { float v = acc[m][n][j]; s += v * v; }
#pragma unroll
        for (int mm = 1; mm < 16; mm <<= 1) s += __shfl_xor(s, mm);
        float rs = rsqrtf(s * (1.0f / 128.0f) + 1.1920929e-07f) * gm;
        int row = brow + wr2 + m * 16 + lg * 4 + j;   // token position
#pragma unroll
        for (int n = 0; n < 2; ++n) {
          float fr = __expf(-(float)(n * 16 + lr) * 0.28782313662425574f); // ln(1e4)/32
          float f = (float)row * fr;
          float c = cosf(f), sn = sinf(f);
          float a1 = acc[m][n][j], a2 = acc[m][n + 2][j];
          acc[m][n][j] = a1 * c + a2 * sn;
          acc[m][n + 2][j] = a2 * c - a1 * sn;
        }
#pragma unroll
        for (int n = 0; n < 8; ++n)
          q16[(size_t)row * 2048 + (hh << 7) + n * 16 + lr] = f2bf(acc[m][n][j] * rs);
      }
  } else {
#pragma unroll
    for (int m = 0; m < 2; ++m)
#pragma unroll
      for (int j = 0; j < 4; ++j) {
        int row = brow + wr2 + m * 16 + lg * 4 + j;
#pragma unroll
        for (int n = 0; n < 8; ++n)
          z16[(size_t)row * 256 + bcol + n * 16 + lr] = f2bf(acc[m][n][j]);
      }
  }
}

// ---------------------------------------------------------------------------
// Fused MLP middle: parts[z] = relu^2(rb1 @ fcA^T)_chunk @ fc2B_chunk^T
// z=16 config (4 chunks/block)  [VALIDATED R15]
// ---------------------------------------------------------------------------
__global__ __launch_bounds__(256, 2) void mlp_mid_k(
    const u16* __restrict__ rb1, const u16* __restrict__ fcA,
    const u16* __restrict__ fc2B, float* __restrict__ parts)
{
  __shared__ u16 Hs[128 * 128];
  const int t = threadIdx.x, w = t >> 6, l = t & 63;
  const int lr = l & 15, lg = l >> 4;
  const int brow = blockIdx.x << 7;
  const int z = blockIdx.z;
  const int hidOff = (w >> 1) << 6, mOff = (w & 1) << 6;   // hop1 wave layout
  const int mOff2 = (w >> 1) << 6, r2Off = (w & 1) << 6;   // hop2 wave layout
  f32x4 acc2[4][4] = {};
#pragma unroll 1
  for (int cc = 0; cc < 4; ++cc) {
    const int H0 = (z * 4 + cc) << 7;
    bf16x8 rb1F[4][4];
#pragma unroll
    for (int mt = 0; mt < 4; ++mt)
#pragma unroll
      for (int ks = 0; ks < 4; ++ks)
        rb1F[mt][ks] = *(const bf16x8*)(rb1 + (size_t)(brow + mOff + mt * 16 + lr) * 128 + ks * 32 + lg * 8);
    f32x4 acc1[4][4] = {};   // [hn][mt]
#pragma unroll
    for (int hn = 0; hn < 4; ++hn) {
      bf16x8 aF[4];
#pragma unroll
      for (int ks = 0; ks < 4; ++ks)
        aF[ks] = *(const bf16x8*)(fcA + (size_t)(H0 + hidOff + hn * 16 + lr) * 128 + ks * 32 + lg * 8);
#pragma unroll
      for (int mt = 0; mt < 4; ++mt)
#pragma unroll
        for (int ks = 0; ks < 4; ++ks)
          acc1[hn][mt] = __builtin_amdgcn_mfma_f32_16x16x32_bf16(aF[ks], rb1F[mt][ks], acc1[hn][mt], 0, 0, 0);
    }
#pragma unroll
    for (int hn = 0; hn < 4; ++hn)
#pragma unroll
      for (int mt = 0; mt < 4; ++mt) {
        float r0 = acc1[hn][mt][0] > 0.f ? acc1[hn][mt][0] * acc1[hn][mt][0] : 0.f;
        float r1 = acc1[hn][mt][1] > 0.f ? acc1[hn][mt][1] * acc1[hn][mt][1] : 0.f;
        float r2 = acc1[hn][mt][2] > 0.f ? acc1[hn][mt][2] * acc1[hn][mt][2] : 0.f;
        float r3 = acc1[hn][mt][3] > 0.f ? acc1[hn][mt][3] * acc1[hn][mt][3] : 0.f;
        uint2 pk; pk.x = cvtpk(r0, r1); pk.y = cvtpk(r2, r3);
        int m = mOff + mt * 16 + lr;
        int hl = hidOff + hn * 16 + lg * 4;
        int cg = hl >> 3;
        *(uint2*)((char*)Hs + m * 256 + (((cg ^ (m & 7)) << 4) | ((hl & 7) << 1))) = pk;
      }
    __syncthreads();
#pragma unroll
    for (int ks2 = 0; ks2 < 4; ++ks2) {
      bf16x8 hF[4];
#pragma unroll
      for (int mt = 0; mt < 4; ++mt) {
        int m = mOff2 + mt * 16 + lr;
        int hl = ks2 * 32 + lg * 8;
        int cg = hl >> 3;
        hF[mt] = *(const bf16x8*)((const char*)Hs + m * 256 + (((cg ^ (m & 7)) << 4)));
      }
#pragma unroll
      for (int nf = 0; nf < 4; ++nf) {
        bf16x8 bF = *(const bf16x8*)(fc2B + (size_t)(r2Off + nf * 16 + lr) * 8192 + H0 + ks2 * 32 + lg * 8);
#pragma unroll
        for (int mt = 0; mt < 4; ++mt)
          acc2[mt][nf] = __builtin_amdgcn_mfma_f32_16x16x32_bf16(hF[mt], bF, acc2[mt][nf], 0, 0, 0);
      }
    }
    __syncthreads();
  }
  float* P = parts + (size_t)z * 2048 * 128;
#pragma unroll
  for (int mt = 0; mt < 4; ++mt)
#pragma unroll
    for (int nf = 0; nf < 4; ++nf)
#pragma unroll
      for (int j = 0; j < 4; ++j)
        P[(size_t)(brow + mOff2 + mt * 16 + lg * 4 + j) * 128 + r2Off + nf * 16 + lr] = acc2[mt][nf][j];
}

// Sum split-K partials -> bf16 (vectorized: n4 = n/4)
__global__ __launch_bounds__(256) void redcvt_k(const float* __restrict__ parts,
                                                u16* __restrict__ out, int n4, int S)
{
  int i = blockIdx.x * 256 + threadIdx.x;
  if (i >= n4) return;
  float4 s = make_float4(0.f, 0.f, 0.f, 0.f);
  for (int z = 0; z < S; ++z) {
    float4 v = ((const float4*)parts)[(size_t)z * n4 + i];
    s.x += v.x; s.y += v.y; s.z += v.z; s.w += v.w;
  }
  uint2 o; o.x = cvtpk(s.x, s.y); o.y = cvtpk(s.z, s.w);
  ((uint2*)out)[i] = o;
}

// ---------------------------------------------------------------------------
// Fused prep: weight f32->bf16 conversion + attn rmsnorm + value-emb rank GEMM
// ---------------------------------------------------------------------------
struct ConvArgs { const float* s[15]; int off[16]; };

__device__ __forceinline__ void rms_body(const float* __restrict__ xr,
                                         const float* __restrict__ wg,
                                         u16* __restrict__ orow, float eps,
                                         __shared__ float* red)
{
  float v[8]; float ss = 0.f;
#pragma unroll
  for (int i = 0; i < 8; ++i) { v[i] = xr[threadIdx.x + i * 256]; ss += v[i] * v[i]; }
#pragma unroll
  for (int m = 1; m < 64; m <<= 1) ss += __shfl_xor(ss, m);
  if ((threadIdx.x & 63) == 0) red[threadIdx.x >> 6] = ss;
  __syncthreads();
  float tot = red[0] + red[1] + red[2] + red[3];
  float rs = rsqrtf(tot * (1.0f / DIMN) + eps);
#pragma unroll
  for (int i = 0; i < 8; ++i) { int c = threadIdx.x + i * 256; orow[c] = f2bf(v[i] * rs * wg[c]); }
}

__global__ __launch_bounds__(256) void prep_k(ConvArgs a, u16* __restrict__ dst,
                                              const float* __restrict__ x,
                                              const float* __restrict__ anw,
                                              u16* __restrict__ xa,
                                              const int* __restrict__ ids,
                                              const float* __restrict__ emb,
                                              const float* __restrict__ vpB,
                                              u16* __restrict__ t16)
{
  __shared__ float red[4];
  const int b = blockIdx.x;
  if (b < 2792) {
    int i = b * 256 + threadIdx.x;
    if (i >= 714752) return;
    int i8 = i * 8;
    int seg = 0;
#pragma unroll
    for (int k = 1; k < 15; ++k) if (i8 >= a.off[k]) seg = k;
    const float* s = a.s[seg] + (i8 - a.off[seg]);
    float4 f0 = *(const float4*)s, f1 = *(const float4*)(s + 4);
    uint4 o; o.x = cvtpk(f0.x, f0.y); o.y = cvtpk(f0.z, f0.w);
    o.z = cvtpk(f1.x, f1.y); o.w = cvtpk(f1.z, f1.w);
    *(uint4*)(dst + i8) = o;
  } else if (b < 2792 + 2048) {
    int row = b - 2792;
    rms_body(x + (size_t)row * DIMN, anw, xa + (size_t)row * DIMN, 1e-6f, red);
  } else {
    int idx = (b - 4840) * 256 + threadIdx.x;   // 2048*32
    int m = idx >> 5, n = idx & 31;
    int id = ids[m]; id = id < 0 ? 0 : (id > 50256 ? 50256 : id);
    const float* e = emb + (size_t)id * 64;
    const float* wr = vpB + n * 64;
    float s = 0.f;
#pragma unroll
    for (int k = 0; k < 64; ++k) s += e[k] * wr[k];
    t16[idx] = f2bf(s);
  }
}

// rmsnorm (standalone, mlp)
__global__ __launch_bounds__(256) void rmsnorm_k(const float* __restrict__ x,
                                                 const float* __restrict__ wg,
                                                 u16* __restrict__ o, float eps)
{
  __shared__ float red[4];
  int row = blockIdx.x;
  rms_body(x + (size_t)row * DIMN, wg, o + (size_t)row * DIMN, eps, red);
}

// vt[d][t] = bf16(v32[t][d]) via 64x64 LDS tile transpose  [proven]
__global__ __launch_bounds__(256) void vtprep_k(const float* __restrict__ v32, u16* __restrict__ vt)
{
  __shared__ float tile[64][65];
  const int t0 = blockIdx.x << 6;
  const int d0 = blockIdx.y << 6;
  int tr = threadIdx.x >> 4;
  int c4 = threadIdx.x & 15;
#pragma unroll
  for (int i = 0; i < 4; ++i) {
    int row = tr + i * 16;
    float4 v = *(const float4*)(v32 + (size_t)(t0 + row) * 512 + d0 + c4 * 4);
    tile[row][c4 * 4 + 0] = v.x; tile[row][c4 * 4 + 1] = v.y;
    tile[row][c4 * 4 + 2] = v.z; tile[row][c4 * 4 + 3] = v.w;
  }
  __syncthreads();
  int dl = threadIdx.x >> 2;
  int ts = (threadIdx.x & 3) * 16;
  u16* orow = vt + (size_t)(d0 + dl) * 2048 + t0 + ts;
#pragma unroll
  for (int k = 0; k < 16; k += 2) {
    unsigned int pk = cvtpk(tile[ts + k][dl], tile[ts + k + 1][dl]);
    *(unsigned int*)(orow + k) = pk;
  }
}

// ---------------------------------------------------------------------------
// Flash attention: kv-head-shared, no split, double-buffered counted-vmcnt.
// Grid 256 blocks = (kh, 32 q-rows); 4 waves = 4 heads of kh share K/V tiles.
// ---------------------------------------------------------------------------
__device__ __forceinline__ int read_window(const int* wptr){
  int W = *wptr;
  if (W > 65536 || W < 0) { union { int i; float f; } u; u.i = W; W = (int)u.f; }
  if (W < 1) W = 1;
  if (W > SEQT) W = SEQT;
  return W;
}

__global__ __launch_bounds__(256, 2) void attn_k(
    const u16* __restrict__ Q, const u16* __restrict__ Kx, const u16* __restrict__ Vt,
    u16* __restrict__ O, const int* __restrict__ wptr)
{
  __shared__ u16 Ks[2][64 * 128];
  __shared__ u16 Vs[2][128 * 64];
  __shared__ u16 Pl[4][2][16 * 64];
  const int t = threadIdx.x;
  const int w = t >> 6, l = t & 63;
  const int lr = l & 15, lg = l >> 4;
  const int kh = blockIdx.x >> 6, qb = blockIdx.x & 63;  // flat%8 = qb%8 -> XCD spread
  const int h = kh * 4 + w;                              // wave = head
  const int qb0 = qb << 5;
  const int W = read_window(wptr);
  int kstart = qb0 - W + 1;
  if (kstart < 0) kstart = 0;
  kstart &= ~63;
  const int kc_max = (qb0 + 31) & ~63;
  const int nt = ((kc_max - kstart) >> 6) + 1;
  bf16x8 qF[2][4];
#pragma unroll
  for (int g = 0; g < 2; ++g)
#pragma unroll
    for (int ks = 0; ks < 4; ++ks)
      qF[g][ks] = *(const bf16x8*)(Q + (size_t)(qb0 + g * 16 + lr) * DIMN + h * 128 + ks * 32 + lg * 8);
  f32x4 oacc[2][8] = {};
  float lsum[2] = {0.f, 0.f};
  const int swz = (lr & 7) << 4;
  char* PlB0 = (char*)&Pl[w][0][0] + lr * 128;
  char* PlB1 = (char*)&Pl[w][1][0] + lr * 128;

  auto stage = [&](int buf, int kc){
#pragma unroll
    for (int i = 0; i < 4; ++i) {
      int eo = i * 2048 + t * 8;
      int row = eo >> 7, cg = (eo >> 3) & 15;
      gload_lds16(Kx + (size_t)(kc + row) * 512 + kh * 128 + (((cg ^ row) & 15) << 3), &Ks[buf][eo]);
    }
#pragma unroll
    for (int i = 0; i < 4; ++i) {
      int eo = i * 2048 + t * 8;
      int d = eo >> 6, kg = (eo >> 3) & 7;
      gload_lds16(Vt + (size_t)kh * (128 * SEQT) + (size_t)d * SEQT + kc + (((kg ^ d) & 7) << 3), &Vs[buf][eo]);
    }
  };

  stage(0, kstart);
  for (int tt = 0; tt < nt; ++tt) {
    const int kc = kstart + (tt << 6);
    const int nx = (tt + 1 < nt) ? tt + 1 : tt;   // dummy re-stage on last iter
    stage((tt + 1) & 1, kstart + (nx << 6));
    asm volatile("s_waitcnt vmcnt(8)" ::: "memory");   // tile tt landed; tt+1 in flight
    __builtin_amdgcn_sched_barrier(0);
    __builtin_amdgcn_s_barrier();
    const u16* KsC = &Ks[tt & 1][0];
    const u16* VsC = &Vs[tt & 1][0];
    f32x4 sf0[4] = {}, sf1[4] = {};
#pragma unroll
    for (int ks = 0; ks < 4; ++ks)
#pragma unroll
      for (int n = 0; n < 4; ++n) {
        int row = n * 16 + lr, kg = ks * 4 + lg;
        bf16x8 kF = *(const bf16x8*)&KsC[(row << 7) + (((kg ^ row) & 15) << 3)];
        sf0[n] = __builtin_amdgcn_mfma_f32_16x16x32_bf16(kF, qF[0][ks], sf0[n], 0, 0, 0);
        sf1[n] = __builtin_amdgcn_mfma_f32_16x16x32_bf16(kF, qF[1][ks], sf1[n], 0, 0, 0);
      }
#pragma unroll
    for (int g = 0; g < 2; ++g) {
      f32x4* sf = g ? sf1 : sf0;
      char* PlB = g ? PlB1 : PlB0;
      const int qg0 = qb0 + g * 16;
      const int qi = qg0 + lr;
      const bool fullv = ((kc + 63) <= qg0) && ((qg0 + 15 - kc) < W);
      if (fullv) {
#pragma unroll
        for (int n = 0; n < 4; ++n)
#pragma unroll
          for (int j = 0; j < 4; ++j) {
            float p = fexp2(sf[n][j]);
            sf[n][j] = p; lsum[g] += p;
          }
      } else {
#pragma unroll
        for (int n = 0; n < 4; ++n)
#pragma unroll
          for (int j = 0; j < 4; ++j) {
            int kj = kc + n * 16 + lg * 4 + j;
            bool vld = (kj <= qi) && ((qi - kj) < W);
            float p = vld ? fexp2(sf[n][j]) : 0.f;
            sf[n][j] = p; lsum[g] += p;
          }
      }
#pragma unroll
      for (int n = 0; n < 4; ++n) {
        uint2 pk;
        pk.x = cvtpk(sf[n][0], sf[n][1]);
        pk.y = cvtpk(sf[n][2], sf[n][3]);
        *(uint2*)(PlB + ((n * 32 + lg * 8) ^ swz)) = pk;
      }
    }
#pragma unroll
    for (int ks = 0; ks < 2; ++ks) {
      int kgp = ks * 4 + lg;
      bf16x8 pF0 = *(const bf16x8*)(PlB0 + ((kgp * 16) ^ swz));
      bf16x8 pF1 = *(const bf16x8*)(PlB1 + ((kgp * 16) ^ swz));
#pragma unroll
      for (int nd = 0; nd < 8; ++nd) {
        int d = nd * 16 + lr;
        bf16x8 vF = *(const bf16x8*)&VsC[(d << 6) + (((kgp ^ d) & 7) << 3)];
        oacc[0][nd] = __builtin_amdgcn_mfma_f32_16x16x32_bf16(pF0, vF, oacc[0][nd], 0, 0, 0);
        oacc[1][nd] = __builtin_amdgcn_mfma_f32_16x16x32_bf16(pF1, vF, oacc[1][nd], 0, 0, 0);
      }
    }
    __builtin_amdgcn_s_barrier();   // all waves done reading buf before re-stage
  }
#pragma unroll
  for (int g = 0; g < 2; ++g) {
    float ls = lsum[g];
    ls += __shfl_xor(ls, 16);
    ls += __shfl_xor(ls, 32);
    float inv[4];
#pragma unroll
    for (int j = 0; j < 4; ++j) inv[j] = 1.0f / __shfl(ls, lg * 4 + j);
#pragma unroll
    for (int nd = 0; nd < 8; ++nd)
#pragma unroll
      for (int j = 0; j < 4; ++j)
        O[(size_t)(qb0 + g * 16 + lg * 4 + j) * DIMN + h * 128 + nd * 16 + lr] =
            f2bf(oacc[g][nd][j] * inv[j]);
  }
}

// ---------------------------------------------------------------------------
extern "C" void kernel_launch(void* const* d_in, const int* in_sizes, int n_in,
                              void* d_out, int out_size, void* d_ws, size_t ws_size,
                              hipStream_t stream)
{
  (void)in_sizes; (void)n_in; (void)out_size; (void)ws_size;
  const float* x          = (const float*)d_in[0];
  const int*   ids        = (const int*)d_in[1];
  const int*   wptr       = (const int*)d_in[2];
  const float* anw        = (const float*)d_in[3];
  const float* attn_scale = (const float*)d_in[14];
  const float* q_gain     = (const float*)d_in[15];
  const float* vemb       = (const float*)d_in[16];
  const float* vpB        = (const float*)d_in[17];
  const float* mnw        = (const float*)d_in[19];
  const float* mlp_scale  = (const float*)d_in[24];

  char* ws = (char*)d_ws;
  u16* W16 = (u16*)ws;
  static const int WOFF[16] = {0, 524288, 1048576, 1572864, 1638400, 1703936,
                               1769472, 1900544, 2031616, 2555904, 3080192,
                               3096576, 3358720, 4407296, 5455872, 5718016};
  const u16* qkB16   = W16 + WOFF[0];   // 512 x 2048
  const u16* qA16    = W16 + WOFF[2];
  const u16* kvA16   = W16 + WOFF[3];
  const u16* kuvuB16 = W16 + WOFF[4];   // 512 x 256
  const u16* kuA16   = W16 + WOFF[6];
  const u16* vuA16   = W16 + WOFF[7];
  const u16* oB16    = W16 + WOFF[8];
  const u16* oA16    = W16 + WOFF[9];
  const u16* vpA16   = W16 + WOFF[10];
  const u16* fcB16   = W16 + WOFF[11];
  const u16* fcA16   = W16 + WOFF[12];
  const u16* fc2B16  = W16 + WOFF[13];
  const u16* fc2A16  = W16 + WOFF[14];

  u16*   xa16  = (u16*)(ws + 11534336);  // 8MB (norm output, q/kv then mlp)
  u16*   rb1   = (u16*)(ws + 19922944);  // 2MB rank buf
  u16*   z16   = (u16*)(ws + 22020096);  // 1MB kv-latent
  u16*   rb2   = (u16*)(ws + 23068672);  // 2MB ku/vu ranks
  u16*   k16   = (u16*)(ws + 25165824);  // 2MB
  float* v32   = (float*)(ws + 27262976);// 4MB
  u16*   vt16  = (u16*)(ws + 31457280);  // 2MB
  u16*   q16   = (u16*)(ws + 33554432);  // 8MB
  u16*   ao16  = (u16*)(ws + 41943040);  // 8MB
  float* parts = (float*)(ws + 50331648);// <=16MB split-K / mlp partials
  u16*   t16   = (u16*)(ws + 83886080);  // 128KB value-emb rank
  float* x2    = (float*)d_out;

  ConvArgs ca;
  const int widx[15] = {4, 6, 5, 7, 8, 10, 9, 11, 12, 13, 18, 20, 21, 22, 23};
  for (int i = 0; i < 15; ++i) ca.s[i] = (const float*)d_in[widx[i]];
  for (int i = 0; i < 16; ++i) ca.off[i] = WOFF[i];

  // fused prep: weight convert + attn rmsnorm + value-emb rank GEMM
  prep_k<<<5096, 256, 0, stream>>>(ca, W16, x, anw, xa16, ids, vemb, vpB, t16);

  // fused hop1: xa @ [qB;kvB].T  (N=512, split-K 4)
  gemm_nt<64, 0><<<dim3(16, 4, 4), 256, 0, stream>>>(xa16, qkB16, parts, 2048, 512, 2048, 2048, nullptr, nullptr);
  redcvt_k<<<1024, 256, 0, stream>>>(parts, rb1, 262144, 4);
  // merged q (rms+rope+gain epi) + z, one dispatch  [validated R15]
  hop2qz_k<<<dim3(16, 18), 256, 0, stream>>>(rb1, qA16, kvA16, q16, z16, q_gain);
  // fused ku/vu hop1: z @ [kuB;vuB].T  (N=512)
  gemm_nt<64, 1><<<dim3(16, 4, 1), 256, 0, stream>>>(z16, kuvuB16, rb2, 2048, 512, 256, 256, nullptr, nullptr);
  // merged k (rms epi) + v (DUAL tail, plain f32 store), one dispatch
  hop2kv_k<<<dim3(16, 8), 256, 0, stream>>>(rb2, kuA16, vuA16, k16, v32, t16, vpA16);
  vtprep_k<<<dim3(32, 8), 256, 0, stream>>>(v32, vt16);
  // attention (single pass, direct bf16 out)
  attn_k<<<256, 256, 0, stream>>>(q16, k16, vt16, ao16, wptr);
  // o-proj: hop1 split-8, redcvt, hop2 fused with residual (x + sc*o)
  gemm_nt<64, 0><<<dim3(16, 2, 8), 256, 0, stream>>>(ao16, oB16, parts, 2048, 256, 2048, 2048, nullptr, nullptr);
  redcvt_k<<<512, 256, 0, stream>>>(parts, rb1, 131072, 8);
  gemm_nt<64, 4><<<dim3(16, 16, 1), 256, 0, stream>>>(rb1, oA16, x2, 2048, 2048, 256, 256, x, attn_scale);
  // mlp
  rmsnorm_k<<<2048, 256, 0, stream>>>(x2, mnw, xa16, 1e-6f);
  gemm_nt<64, 0><<<dim3(16, 1, 8), 256, 0, stream>>>(xa16, fcB16, parts, 2048, 128, 2048, 2048, nullptr, nullptr);
  redcvt_k<<<256, 256, 0, stream>>>(parts, rb1, 65536, 8);
  mlp_mid_k<<<dim3(16, 1, 16), 256, 0, stream>>>(rb1, fcA16, fc2B16, parts);
  redcvt_k<<<256, 256, 0, stream>>>(parts, rb1, 65536, 16);
  gemm_nt<64, 4><<<dim3(16, 16, 1), 256, 0, stream>>>(rb1, fc2A16, x2, 2048, 2048, 128, 128, x2, mlp_scale);
}